// Round 2
// baseline (7912.131 us; speedup 1.0000x reference)
//
#include <hip/hip_runtime.h>
#include <cfloat>

// Problem constants (match reference setup_inputs)
constexpr int NB = 8, NN = 3000, NM = 3000, KK = 8;
constexpr int CAP = 48;                       // per-row/col sparse capacity: 8 base + up to 40 extras
constexpr int SUBS = 8, COLS = 64;            // column-topk tiling
constexpr int RPS = NN / SUBS;                // rows per sub-chunk = 375
constexpr float SCALE   = 14.426950408889634f;   // 1/(EPS*ln2), EPS=0.1
constexpr float UNSCALE = 0.06931471805599453f;  // EPS*ln2
constexpr float THRESH  = 0.1f;

// Cooperative sinkhorn geometry
constexpr int BPB  = 32;                      // blocks per batch
constexpr int NBLK = NB * BPB;                // 256 blocks
constexpr int TPB  = 128;                     // threads per block
constexpr int RPB  = (NN + BPB - 1) / BPB;    // rows per block = 94
// ctrl layout (int indices, padded to separate cache lines)
#define CTRL_GROUP(b) ((b) * 32)
constexpr int CTRL_ROOT = 8 * 32;
constexpr int CTRL_GEN  = 9 * 32;
constexpr int CTRL_MASK = 10 * 32;
constexpr int CTRL_INTS = 512;

#if __has_builtin(__builtin_amdgcn_exp2f)
#define FEXP2(x) __builtin_amdgcn_exp2f(x)
#else
#define FEXP2(x) exp2f(x)
#endif
#if __has_builtin(__builtin_amdgcn_logf)
#define FLOG2(x) __builtin_amdgcn_logf(x)   // v_log_f32 = log2
#else
#define FLOG2(x) __log2f(x)
#endif

// ---------------------------------------------------------------------------
// K1: per-(b,n) row: L2 norm + top-8 smallest (indices). Row staged in LDS.
// ---------------------------------------------------------------------------
__global__ __launch_bounds__(256) void k_rowprep(const float* __restrict__ C,
                                                 float* __restrict__ norms,
                                                 int* __restrict__ rowsel) {
  int bn = blockIdx.x;                       // b*NN + n
  const float* row = C + (size_t)bn * NM;
  __shared__ __align__(16) float lds[NM];
  __shared__ float rv[4];
  __shared__ int   ri[4];
  int tid = threadIdx.x;
  float sq = 0.f;
  for (int i = tid; i < NM / 4; i += 256) {
    float4 f = reinterpret_cast<const float4*>(row)[i];
    reinterpret_cast<float4*>(lds)[i] = f;
    sq += f.x * f.x + f.y * f.y + f.z * f.z + f.w * f.w;
  }
#pragma unroll
  for (int o = 32; o; o >>= 1) sq += __shfl_down(sq, o);
  int wid = tid >> 6, lane = tid & 63;
  if (lane == 0) rv[wid] = sq;
  __syncthreads();
  if (tid == 0) norms[bn] = sqrtf(rv[0] + rv[1] + rv[2] + rv[3]);
  __syncthreads();  // rv reused below

  for (int p = 0; p < KK; ++p) {
    float mv = FLT_MAX; int mi = NM;
    for (int i = tid; i < NM; i += 256) {
      float v = lds[i];
      if (v < mv) { mv = v; mi = i; }        // strided asc indices -> stable
    }
#pragma unroll
    for (int o = 32; o; o >>= 1) {
      float ov = __shfl_down(mv, o); int oi = __shfl_down(mi, o);
      if (ov < mv || (ov == mv && oi < mi)) { mv = ov; mi = oi; }
    }
    if (lane == 0) { rv[wid] = mv; ri[wid] = mi; }
    __syncthreads();
    if (tid == 0) {
      float bv = rv[0]; int bi = ri[0];
#pragma unroll
      for (int w = 1; w < 4; ++w)
        if (rv[w] < bv || (rv[w] == bv && ri[w] < bi)) { bv = rv[w]; bi = ri[w]; }
      rowsel[(size_t)bn * KK + p] = bi;
      lds[bi] = FLT_MAX;                     // exclude for next pass
    }
    __syncthreads();
  }
}

// ---------------------------------------------------------------------------
// K2: per-(b,m) column: top-8 largest of C/norm.
// ---------------------------------------------------------------------------
__global__ __launch_bounds__(512) void k_coltop(const float* __restrict__ C,
                                                const float* __restrict__ norms,
                                                int* __restrict__ colsel) {
  int b = blockIdx.y;
  int cg = blockIdx.x;
  int tid = threadIdx.x;
  int col = tid & (COLS - 1);
  int sub = tid >> 6;                         // 0..7
  int m = cg * COLS + col;
  __shared__ float inv[NN];
  __shared__ float sv[SUBS * COLS * 8];
  __shared__ int   si[SUBS * COLS * 8];
  for (int r = tid; r < NN; r += 512)
    inv[r] = 1.0f / fmaxf(norms[(size_t)b * NN + r], 1e-12f);
  __syncthreads();

  float tv[8]; int ti[8];
#pragma unroll
  for (int q = 0; q < 8; ++q) { tv[q] = -FLT_MAX; ti[q] = 0x7fffffff; }

  if (m < NM) {
    const float* base = C + ((size_t)b * NN + (size_t)sub * RPS) * NM + m;
    for (int r = 0; r < RPS; r += 5) {        // 375 = 5*75
#pragma unroll
      for (int j = 0; j < 5; ++j) {
        int rr = r + j;
        float val = base[(size_t)rr * NM] * inv[sub * RPS + rr];
        if (val > tv[7]) {                    // stable insert (ties keep earlier n)
          int idx = sub * RPS + rr;
          int pos = 8;
#pragma unroll
          for (int q = 7; q >= 0; --q) if (val > tv[q]) pos = q;
#pragma unroll
          for (int q = 7; q >= 1; --q) if (q > pos) { tv[q] = tv[q-1]; ti[q] = ti[q-1]; }
#pragma unroll
          for (int q = 0; q < 8; ++q) if (q == pos) { tv[q] = val; ti[q] = idx; }
        }
      }
    }
  }
#pragma unroll
  for (int q = 0; q < 8; ++q) { sv[tid * 8 + q] = tv[q]; si[tid * 8 + q] = ti[q]; }
  __syncthreads();

  if (tid < COLS) {
    int mcol = cg * COLS + tid;
    if (mcol < NM) {
      unsigned long long used = 0;
      for (int p = 0; p < KK; ++p) {
        float bv = -FLT_MAX; int bi = 0x7fffffff; int bq = 0;
        for (int c = 0; c < SUBS; ++c) {
#pragma unroll
          for (int q = 0; q < 8; ++q) {
            int bit = c * 8 + q;
            if ((used >> bit) & 1ull) continue;
            float v = sv[(c * COLS + tid) * 8 + q];
            int   n = si[(c * COLS + tid) * 8 + q];
            if (v > bv || (v == bv && n < bi)) { bv = v; bi = n; bq = bit; }
          }
        }
        used |= 1ull << bq;
        colsel[((size_t)b * NM + mcol) * KK + p] = bi;
      }
    }
  }
}

// ---------------------------------------------------------------------------
// K3: fill base slots (0..7) of CSR (rows) and CSC (cols).
// ---------------------------------------------------------------------------
__global__ __launch_bounds__(256) void k_fillbase(const float* __restrict__ C,
    const float* __restrict__ norms, const int* __restrict__ rowsel,
    const int* __restrict__ colsel, int2* __restrict__ r_pk, int2* __restrict__ c_pk) {
  int t = blockIdx.x * 256 + threadIdx.x;
  if (t >= NB * NN * KK) return;
  int k = t % KK; int bn = t / KK;
  int b = bn / NN; int n = bn % NN;
  {
    int m = rowsel[t];
    float iv = 1.0f / fmaxf(norms[bn], 1e-12f);
    float v2 = C[((size_t)b * NN + n) * NM + m] * iv * SCALE;
    r_pk[(size_t)bn * CAP + k] = make_int2(m, __float_as_int(v2));
  }
  {
    int m2 = bn % NM;                         // reinterpret bn as b*NM+m
    int n2 = colsel[t];
    float iv = 1.0f / fmaxf(norms[(size_t)b * NN + n2], 1e-12f);
    float v2 = C[((size_t)b * NN + n2) * NM + m2] * iv * SCALE;
    c_pk[(size_t)bn * CAP + k] = make_int2(n2, __float_as_int(v2));
  }
  (void)k;
}

// ---------------------------------------------------------------------------
// K4: append non-duplicate extras.
// ---------------------------------------------------------------------------
__global__ __launch_bounds__(256) void k_fillextra(const float* __restrict__ C,
    const float* __restrict__ norms, const int* __restrict__ rowsel,
    const int* __restrict__ colsel, int* r_cnt, int* c_cnt,
    int2* __restrict__ r_pk, int2* __restrict__ c_pk) {
  int t = blockIdx.x * 256 + threadIdx.x;
  if (t >= NB * NM * KK) return;
  int bm = t / KK;
  int b = bm / NM; int m = bm % NM;
  {  // colsel entry (b,m,k): row n gains column m unless duplicate
    int n = colsel[t];
    const int* rs = rowsel + ((size_t)b * NN + n) * KK;
    bool dup = false;
#pragma unroll
    for (int q = 0; q < KK; ++q) dup |= (rs[q] == m);
    if (!dup) {
      int slot = 8 + atomicAdd(&r_cnt[(size_t)b * NN + n], 1);
      if (slot < CAP) {
        float iv = 1.0f / fmaxf(norms[(size_t)b * NN + n], 1e-12f);
        float v2 = C[((size_t)b * NN + n) * NM + m] * iv * SCALE;
        r_pk[((size_t)b * NN + n) * CAP + slot] = make_int2(m, __float_as_int(v2));
      }
    }
  }
  {  // rowsel entry (b,n2,k): column mm gains row n2 unless duplicate
    int n2 = m;
    int mm = rowsel[t];
    const int* cs = colsel + ((size_t)b * NM + mm) * KK;
    bool dup = false;
#pragma unroll
    for (int q = 0; q < KK; ++q) dup |= (cs[q] == n2);
    if (!dup) {
      int slot = 8 + atomicAdd(&c_cnt[(size_t)b * NM + mm], 1);
      if (slot < CAP) {
        float iv = 1.0f / fmaxf(norms[(size_t)b * NN + n2], 1e-12f);
        float v2 = C[((size_t)b * NN + n2) * NM + mm] * iv * SCALE;
        c_pk[((size_t)b * NM + mm) * CAP + slot] = make_int2(n2, __float_as_int(v2));
      }
    }
  }
}

// ---------------------------------------------------------------------------
// Two-level device-scope grid barrier: 8 group counters -> root -> gen spin.
// Requires all NBLK blocks co-resident (cooperative launch guarantees it).
// ---------------------------------------------------------------------------
__device__ inline void gbar(int* ctrl, int b, int& mygen) {
  __syncthreads();
  if (threadIdx.x == 0) {
    __threadfence();                           // release this block's writes
    int p = __hip_atomic_fetch_add(&ctrl[CTRL_GROUP(b)], 1, __ATOMIC_ACQ_REL,
                                   __HIP_MEMORY_SCOPE_AGENT);
    if (p == BPB - 1) {
      __hip_atomic_store(&ctrl[CTRL_GROUP(b)], 0, __ATOMIC_RELAXED,
                         __HIP_MEMORY_SCOPE_AGENT);
      int q = __hip_atomic_fetch_add(&ctrl[CTRL_ROOT], 1, __ATOMIC_ACQ_REL,
                                     __HIP_MEMORY_SCOPE_AGENT);
      if (q == NB - 1) {
        __hip_atomic_store(&ctrl[CTRL_ROOT], 0, __ATOMIC_RELAXED,
                           __HIP_MEMORY_SCOPE_AGENT);
        __hip_atomic_store(&ctrl[CTRL_GEN], mygen + 1, __ATOMIC_RELEASE,
                           __HIP_MEMORY_SCOPE_AGENT);
      }
    }
    while (__hip_atomic_load(&ctrl[CTRL_GEN], __ATOMIC_ACQUIRE,
                             __HIP_MEMORY_SCOPE_AGENT) <= mygen) {
      __builtin_amdgcn_s_sleep(1);
    }
    __threadfence();                           // acquire remote writes
    mygen++;
  }
  __syncthreads();
}

// ---------------------------------------------------------------------------
// K5 (cooperative): whole-chip sparse Sinkhorn. 32 blocks/batch, 1 row + 1 col
// per thread, potentials in registers, U/V exchanged via global (L2-resident).
// Iteration math identical to the validated single-block version.
// ---------------------------------------------------------------------------
__global__ __launch_bounds__(TPB) void k_sink_coop(
    const float* __restrict__ mu, const float* __restrict__ nu,
    const int2* __restrict__ r_pk, const int* __restrict__ r_cnt,
    const int2* __restrict__ c_pk, const int* __restrict__ c_cnt,
    float* __restrict__ U_g, float* __restrict__ V_g,
    float* __restrict__ errpart, int* ctrl, float* __restrict__ costpart) {
  const int blk = blockIdx.x;
  const int b = blk / BPB, slice = blk % BPB;
  const int tid = threadIdx.x;
  const int r = slice * RPB + tid;            // row/col this thread owns
  const bool has_r = (tid < RPB) && (r < NN); // NN == NM: same geometry for cols
  float* Ub = U_g + (size_t)b * NN;
  float* Vb = V_g + (size_t)b * NM;

  float u = 0.f, v = 0.f, lmu = 0.f, lnu = 0.f;
  const int2* rp = nullptr; const int2* cp = nullptr;
  int cntr = 0, cntc = 0;
  if (has_r) {
    rp = r_pk + ((size_t)b * NN + r) * CAP;
    cntr = 8 + min(r_cnt[(size_t)b * NN + r], CAP - 8);
    lmu = FLOG2(mu[(size_t)b * NN + r] + 1e-8f);
    cp = c_pk + ((size_t)b * NM + r) * CAP;
    cntc = 8 + min(c_cnt[(size_t)b * NM + r], CAP - 8);
    lnu = FLOG2(nu[(size_t)b * NM + r] + 1e-8f);
  }

  __shared__ float sred[TPB / 64];
  int mygen = 0;

  for (int it = 0; it < 100; ++it) {
    int mask = (it == 0) ? 0
             : __hip_atomic_load(&ctrl[CTRL_MASK], __ATOMIC_RELAXED,
                                 __HIP_MEMORY_SCOPE_AGENT);
    if (mask == 0xFF) break;
    const bool act = !((mask >> b) & 1);

    // ---- Phase A: u update ----
    float errp = 0.f;
    if (act && has_r) {
      float s = 0.f;
      for (int e = 0; e < cntr; ++e) {
        int2 pk = rp[e];
        s += FEXP2(u + Vb[pk.x] - __int_as_float(pk.y));
      }
      float un = lmu - FLOG2(1e-8f + s) + u;
      errp = fabsf(un - u);
      u = un;
      Ub[r] = un;
    }
    if (act) {
#pragma unroll
      for (int o = 32; o; o >>= 1) errp += __shfl_down(errp, o);
      if ((tid & 63) == 0) sred[tid >> 6] = errp;
    }
    __syncthreads();
    if (act && tid == 0) errpart[b * BPB + slice] = sred[0] + sred[1];
    gbar(ctrl, b, mygen);

    // ---- Phase B: v update (+ designated done-mask update) ----
    if (act && has_r) {
      float s = 0.f;
      for (int e = 0; e < cntc; ++e) {
        int2 pk = cp[e];
        s += FEXP2(Ub[pk.x] + v - __int_as_float(pk.y));
      }
      v = lnu - FLOG2(1e-8f + s) + v;
      Vb[r] = v;
    }
    if (blk == 0 && tid == TPB - 1) {
      int m = mask;
      for (int bb = 0; bb < NB; ++bb) {
        if ((m >> bb) & 1) continue;
        float tot = 0.f;
        for (int ss = 0; ss < BPB; ++ss) tot += errpart[bb * BPB + ss];
        if (tot * UNSCALE < THRESH) m |= (1 << bb);
      }
      __hip_atomic_store(&ctrl[CTRL_MASK], m, __ATOMIC_RELAXED,
                         __HIP_MEMORY_SCOPE_AGENT);
    }
    gbar(ctrl, b, mygen);
  }

  // ---- cost partial: sum pi*val over this block's rows ----
  float cs = 0.f;
  if (has_r) {
    for (int e = 0; e < cntr; ++e) {
      int2 pk = rp[e];
      float val = __int_as_float(pk.y);
      cs += FEXP2(u + Vb[pk.x] - val) * val;
    }
  }
#pragma unroll
  for (int o = 32; o; o >>= 1) cs += __shfl_down(cs, o);
  if ((tid & 63) == 0) sred[tid >> 6] = cs;
  __syncthreads();
  if (tid == 0) costpart[b * BPB + slice] = sred[0] + sred[1];
}

// Deterministic final reduction: fixed-order sums.
__global__ void k_final2(const float* __restrict__ costpart, float* __restrict__ out) {
  if (threadIdx.x == 0 && blockIdx.x == 0) {
    float tot = 0.f;
    for (int b = 0; b < NB; ++b) {
      float cb = 0.f;
      for (int s = 0; s < BPB; ++s) cb += costpart[b * BPB + s];
      tot += cb * UNSCALE;
    }
    out[0] = tot * (1.0f / NB);
  }
}

// ---------------------------------------------------------------------------
extern "C" void kernel_launch(void* const* d_in, const int* in_sizes, int n_in,
                              void* d_out, int out_size, void* d_ws, size_t ws_size,
                              hipStream_t stream) {
  const float* mu = (const float*)d_in[0];
  const float* nu = (const float*)d_in[1];
  const float* C  = (const float*)d_in[2];
  float* out = (float*)d_out;

  char* ws = (char*)d_ws;
  size_t off = 0;
  auto alloc = [&](size_t bytes) {
    void* p = ws + off;
    off += (bytes + 255) & ~(size_t)255;
    return p;
  };
  float* norms    = (float*)alloc(sizeof(float) * NB * NN);
  int*   rowsel   = (int*)  alloc(sizeof(int)   * NB * NN * KK);
  int*   colsel   = (int*)  alloc(sizeof(int)   * NB * NM * KK);
  int*   r_cnt    = (int*)  alloc(sizeof(int)   * NB * NN);
  int*   c_cnt    = (int*)  alloc(sizeof(int)   * NB * NM);
  int2*  r_pk     = (int2*) alloc(sizeof(int2)  * NB * NN * CAP);
  int2*  c_pk     = (int2*) alloc(sizeof(int2)  * NB * NM * CAP);
  float* U_g      = (float*)alloc(sizeof(float) * NB * NN);
  float* V_g      = (float*)alloc(sizeof(float) * NB * NM);
  float* errpart  = (float*)alloc(sizeof(float) * NB * BPB);
  float* costpart = (float*)alloc(sizeof(float) * NB * BPB);
  int*   ctrl     = (int*)  alloc(sizeof(int)   * CTRL_INTS);
  (void)ws_size; (void)in_sizes; (void)n_in; (void)out_size;

  hipMemsetAsync(r_cnt, 0, sizeof(int) * NB * NN, stream);
  hipMemsetAsync(c_cnt, 0, sizeof(int) * NB * NM, stream);
  size_t span = (size_t)((char*)ctrl - (char*)U_g) + sizeof(int) * CTRL_INTS;
  hipMemsetAsync(U_g, 0, span, stream);        // U, V, errpart, costpart, ctrl

  hipLaunchKernelGGL(k_rowprep, dim3(NB * NN), dim3(256), 0, stream, C, norms, rowsel);
  hipLaunchKernelGGL(k_coltop, dim3((NM + COLS - 1) / COLS, NB), dim3(512), 0, stream,
                     C, norms, colsel);
  int nthreads = NB * NN * KK;
  hipLaunchKernelGGL(k_fillbase, dim3((nthreads + 255) / 256), dim3(256), 0, stream,
                     C, norms, rowsel, colsel, r_pk, c_pk);
  hipLaunchKernelGGL(k_fillextra, dim3((nthreads + 255) / 256), dim3(256), 0, stream,
                     C, norms, rowsel, colsel, r_cnt, c_cnt, r_pk, c_pk);

  void* args[] = { (void*)&mu, (void*)&nu, (void*)&r_pk, (void*)&r_cnt,
                   (void*)&c_pk, (void*)&c_cnt, (void*)&U_g, (void*)&V_g,
                   (void*)&errpart, (void*)&ctrl, (void*)&costpart };
  hipLaunchCooperativeKernel((const void*)k_sink_coop, dim3(NBLK), dim3(TPB),
                             args, 0, stream);

  hipLaunchKernelGGL(k_final2, dim3(1), dim3(64), 0, stream, costpart, out);
}

// Round 3
// 2435.560 us; speedup vs baseline: 3.2486x; 3.2486x over previous
//
#include <hip/hip_runtime.h>
#include <cfloat>

// Problem constants (match reference setup_inputs)
constexpr int NB = 8, NN = 3000, NM = 3000, KK = 8;
constexpr int CAP = 48;                       // per-row/col sparse capacity
constexpr int SUBS = 8, COLS = 64;            // column-topk tiling
constexpr int RPS = NN / SUBS;                // rows per sub-chunk = 375
constexpr float SCALE   = 14.426950408889634f;   // 1/(EPS*ln2), EPS=0.1
constexpr float UNSCALE = 0.06931471805599453f;  // EPS*ln2
constexpr float THRESH  = 0.1f;

// Cooperative sinkhorn geometry: 16 blocks/batch, batch = blockIdx % 8 (XCD-local)
constexpr int BPB  = 16;
constexpr int NBLK = NB * BPB;                // 128 blocks
constexpr int TPB  = 256;
constexpr int RPB  = (NN + BPB - 1) / BPB;    // 188 rows per block

#if __has_builtin(__builtin_amdgcn_exp2f)
#define FEXP2(x) __builtin_amdgcn_exp2f(x)
#else
#define FEXP2(x) exp2f(x)
#endif
#if __has_builtin(__builtin_amdgcn_logf)
#define FLOG2(x) __builtin_amdgcn_logf(x)   // v_log_f32 = log2
#else
#define FLOG2(x) __log2f(x)
#endif

// Relaxed agent-scope atomics: plain sc1 accesses (coherence point), NO cache
// flushes (acquire/release at agent scope would emit buffer_inv/buffer_wbl2 —
// the R2 barrier disaster).
__device__ __forceinline__ float aloadf(const float* p) {
  return __hip_atomic_load(p, __ATOMIC_RELAXED, __HIP_MEMORY_SCOPE_AGENT);
}
__device__ __forceinline__ void astoref(float* p, float x) {
  __hip_atomic_store(p, x, __ATOMIC_RELAXED, __HIP_MEMORY_SCOPE_AGENT);
}
__device__ __forceinline__ int aloadi(const int* p) {
  return __hip_atomic_load(p, __ATOMIC_RELAXED, __HIP_MEMORY_SCOPE_AGENT);
}
__device__ __forceinline__ void astorei(int* p, int x) {
  __hip_atomic_store(p, x, __ATOMIC_RELAXED, __HIP_MEMORY_SCOPE_AGENT);
}

// ---------------------------------------------------------------------------
// K1: per-(b,n) row: L2 norm + top-8 smallest (indices). Row staged in LDS.
// ---------------------------------------------------------------------------
__global__ __launch_bounds__(256) void k_rowprep(const float* __restrict__ C,
                                                 float* __restrict__ norms,
                                                 int* __restrict__ rowsel) {
  int bn = blockIdx.x;                       // b*NN + n
  const float* row = C + (size_t)bn * NM;
  __shared__ __align__(16) float lds[NM];
  __shared__ float rv[4];
  __shared__ int   ri[4];
  int tid = threadIdx.x;
  float sq = 0.f;
  for (int i = tid; i < NM / 4; i += 256) {
    float4 f = reinterpret_cast<const float4*>(row)[i];
    reinterpret_cast<float4*>(lds)[i] = f;
    sq += f.x * f.x + f.y * f.y + f.z * f.z + f.w * f.w;
  }
#pragma unroll
  for (int o = 32; o; o >>= 1) sq += __shfl_down(sq, o);
  int wid = tid >> 6, lane = tid & 63;
  if (lane == 0) rv[wid] = sq;
  __syncthreads();
  if (tid == 0) norms[bn] = sqrtf(rv[0] + rv[1] + rv[2] + rv[3]);
  __syncthreads();  // rv reused below

  for (int p = 0; p < KK; ++p) {
    float mv = FLT_MAX; int mi = NM;
    for (int i = tid; i < NM; i += 256) {
      float v = lds[i];
      if (v < mv) { mv = v; mi = i; }        // strided asc indices -> stable
    }
#pragma unroll
    for (int o = 32; o; o >>= 1) {
      float ov = __shfl_down(mv, o); int oi = __shfl_down(mi, o);
      if (ov < mv || (ov == mv && oi < mi)) { mv = ov; mi = oi; }
    }
    if (lane == 0) { rv[wid] = mv; ri[wid] = mi; }
    __syncthreads();
    if (tid == 0) {
      float bv = rv[0]; int bi = ri[0];
#pragma unroll
      for (int w = 1; w < 4; ++w)
        if (rv[w] < bv || (rv[w] == bv && ri[w] < bi)) { bv = rv[w]; bi = ri[w]; }
      rowsel[(size_t)bn * KK + p] = bi;
      lds[bi] = FLT_MAX;                     // exclude for next pass
    }
    __syncthreads();
  }
}

// ---------------------------------------------------------------------------
// K2: per-(b,m) column: top-8 largest of C/norm.
// ---------------------------------------------------------------------------
__global__ __launch_bounds__(512) void k_coltop(const float* __restrict__ C,
                                                const float* __restrict__ norms,
                                                int* __restrict__ colsel) {
  int b = blockIdx.y;
  int cg = blockIdx.x;
  int tid = threadIdx.x;
  int col = tid & (COLS - 1);
  int sub = tid >> 6;                         // 0..7
  int m = cg * COLS + col;
  __shared__ float inv[NN];
  __shared__ float sv[SUBS * COLS * 8];
  __shared__ int   si[SUBS * COLS * 8];
  for (int r = tid; r < NN; r += 512)
    inv[r] = 1.0f / fmaxf(norms[(size_t)b * NN + r], 1e-12f);
  __syncthreads();

  float tv[8]; int ti[8];
#pragma unroll
  for (int q = 0; q < 8; ++q) { tv[q] = -FLT_MAX; ti[q] = 0x7fffffff; }

  if (m < NM) {
    const float* base = C + ((size_t)b * NN + (size_t)sub * RPS) * NM + m;
    for (int r = 0; r < RPS; r += 5) {        // 375 = 5*75
#pragma unroll
      for (int j = 0; j < 5; ++j) {
        int rr = r + j;
        float val = base[(size_t)rr * NM] * inv[sub * RPS + rr];
        if (val > tv[7]) {                    // stable insert (ties keep earlier n)
          int idx = sub * RPS + rr;
          int pos = 8;
#pragma unroll
          for (int q = 7; q >= 0; --q) if (val > tv[q]) pos = q;
#pragma unroll
          for (int q = 7; q >= 1; --q) if (q > pos) { tv[q] = tv[q-1]; ti[q] = ti[q-1]; }
#pragma unroll
          for (int q = 0; q < 8; ++q) if (q == pos) { tv[q] = val; ti[q] = idx; }
        }
      }
    }
  }
#pragma unroll
  for (int q = 0; q < 8; ++q) { sv[tid * 8 + q] = tv[q]; si[tid * 8 + q] = ti[q]; }
  __syncthreads();

  if (tid < COLS) {
    int mcol = cg * COLS + tid;
    if (mcol < NM) {
      unsigned long long used = 0;
      for (int p = 0; p < KK; ++p) {
        float bv = -FLT_MAX; int bi = 0x7fffffff; int bq = 0;
        for (int c = 0; c < SUBS; ++c) {
#pragma unroll
          for (int q = 0; q < 8; ++q) {
            int bit = c * 8 + q;
            if ((used >> bit) & 1ull) continue;
            float v = sv[(c * COLS + tid) * 8 + q];
            int   n = si[(c * COLS + tid) * 8 + q];
            if (v > bv || (v == bv && n < bi)) { bv = v; bi = n; bq = bit; }
          }
        }
        used |= 1ull << bq;
        colsel[((size_t)b * NM + mcol) * KK + p] = bi;
      }
    }
  }
}

// ---------------------------------------------------------------------------
// K3: fill base slots (0..7) of CSR (rows) and CSC (cols).
// ---------------------------------------------------------------------------
__global__ __launch_bounds__(256) void k_fillbase(const float* __restrict__ C,
    const float* __restrict__ norms, const int* __restrict__ rowsel,
    const int* __restrict__ colsel, int2* __restrict__ r_pk, int2* __restrict__ c_pk) {
  int t = blockIdx.x * 256 + threadIdx.x;
  if (t >= NB * NN * KK) return;
  int k = t % KK; int bn = t / KK;
  int b = bn / NN; int n = bn % NN;
  {
    int m = rowsel[t];
    float iv = 1.0f / fmaxf(norms[bn], 1e-12f);
    float v2 = C[((size_t)b * NN + n) * NM + m] * iv * SCALE;
    r_pk[(size_t)bn * CAP + k] = make_int2(m, __float_as_int(v2));
  }
  {
    int m2 = bn % NM;                         // reinterpret bn as b*NM+m
    int n2 = colsel[t];
    float iv = 1.0f / fmaxf(norms[(size_t)b * NN + n2], 1e-12f);
    float v2 = C[((size_t)b * NN + n2) * NM + m2] * iv * SCALE;
    c_pk[(size_t)bn * CAP + k] = make_int2(n2, __float_as_int(v2));
  }
  (void)k;
}

// ---------------------------------------------------------------------------
// K4: append non-duplicate extras.
// ---------------------------------------------------------------------------
__global__ __launch_bounds__(256) void k_fillextra(const float* __restrict__ C,
    const float* __restrict__ norms, const int* __restrict__ rowsel,
    const int* __restrict__ colsel, int* r_cnt, int* c_cnt,
    int2* __restrict__ r_pk, int2* __restrict__ c_pk) {
  int t = blockIdx.x * 256 + threadIdx.x;
  if (t >= NB * NM * KK) return;
  int bm = t / KK;
  int b = bm / NM; int m = bm % NM;
  {  // colsel entry (b,m,k): row n gains column m unless duplicate
    int n = colsel[t];
    const int* rs = rowsel + ((size_t)b * NN + n) * KK;
    bool dup = false;
#pragma unroll
    for (int q = 0; q < KK; ++q) dup |= (rs[q] == m);
    if (!dup) {
      int slot = 8 + atomicAdd(&r_cnt[(size_t)b * NN + n], 1);
      if (slot < CAP) {
        float iv = 1.0f / fmaxf(norms[(size_t)b * NN + n], 1e-12f);
        float v2 = C[((size_t)b * NN + n) * NM + m] * iv * SCALE;
        r_pk[((size_t)b * NN + n) * CAP + slot] = make_int2(m, __float_as_int(v2));
      }
    }
  }
  {  // rowsel entry (b,n2,k): column mm gains row n2 unless duplicate
    int n2 = m;
    int mm = rowsel[t];
    const int* cs = colsel + ((size_t)b * NM + mm) * KK;
    bool dup = false;
#pragma unroll
    for (int q = 0; q < KK; ++q) dup |= (cs[q] == n2);
    if (!dup) {
      int slot = 8 + atomicAdd(&c_cnt[(size_t)b * NM + mm], 1);
      if (slot < CAP) {
        float iv = 1.0f / fmaxf(norms[(size_t)b * NN + n2], 1e-12f);
        float v2 = C[((size_t)b * NN + n2) * NM + mm] * iv * SCALE;
        c_pk[((size_t)b * NM + mm) * CAP + slot] = make_int2(n2, __float_as_int(v2));
      }
    }
  }
}

// ---------------------------------------------------------------------------
// Fence-free stamped per-batch barrier. 16 blocks/batch. Each block's tid 0:
// s_waitcnt vmcnt(0) (drains its sc1 data stores to the coherence point) then
// stores its stamp to its own arrival slot (no RMW contention). Leader block
// (slice 0) polls the 16-slot line with one wave, optionally folds the
// convergence decision into the generation word: gen = (stamp<<1) | done.
// NO acquire/release -> no buffer_inv / buffer_wbl2.
// ---------------------------------------------------------------------------
__device__ __forceinline__ int bbar(int* arrb, int* genb, float* errb,
                                    int slice, int stamp, bool isA) {
  __shared__ int s_done;
  __syncthreads();                     // compiler drains vmcnt before s_barrier
  int tid = threadIdx.x;
  if (tid < 64) {
    int done = 0;
    if (tid == 0) {
      asm volatile("s_waitcnt vmcnt(0)" ::: "memory");
      astorei(&arrb[slice], stamp);
    }
    if (slice == 0) {
      for (;;) {
        int a = (tid < BPB) ? aloadi(&arrb[tid]) : stamp;
        if (__all(a >= stamp)) break;
        __builtin_amdgcn_s_sleep(2);
      }
      if (isA) {
        float e = (tid < BPB) ? aloadf(&errb[tid]) : 0.f;
        float tot = 0.f;
#pragma unroll
        for (int k = 0; k < BPB; ++k) tot += __shfl(e, k);   // fixed order
        done = (tot * UNSCALE < THRESH) ? 1 : 0;
      }
      if (tid == 0) astorei(genb, (stamp << 1) | done);
    } else if (tid == 0) {
      int g;
      while ((g = aloadi(genb)) < (stamp << 1))
        __builtin_amdgcn_s_sleep(2);
      done = g & 1;
    }
    if (tid == 0) s_done = done;
  }
  __syncthreads();
  return s_done;
}

// Sum of exp2(base + X[idx] - val) over a sparse row; first 8 entries unrolled
// so their 8 gathers issue concurrently (one latency window, not 8 serial).
__device__ __forceinline__ float sprowsum(const int2* __restrict__ p, int cnt,
                                          float base, const float* __restrict__ X) {
  int2 e0 = p[0], e1 = p[1], e2 = p[2], e3 = p[3];
  int2 e4 = p[4], e5 = p[5], e6 = p[6], e7 = p[7];
  float x0 = aloadf(&X[e0.x]), x1 = aloadf(&X[e1.x]);
  float x2 = aloadf(&X[e2.x]), x3 = aloadf(&X[e3.x]);
  float x4 = aloadf(&X[e4.x]), x5 = aloadf(&X[e5.x]);
  float x6 = aloadf(&X[e6.x]), x7 = aloadf(&X[e7.x]);
  float s = FEXP2(base + x0 - __int_as_float(e0.y));
  s += FEXP2(base + x1 - __int_as_float(e1.y));
  s += FEXP2(base + x2 - __int_as_float(e2.y));
  s += FEXP2(base + x3 - __int_as_float(e3.y));
  s += FEXP2(base + x4 - __int_as_float(e4.y));
  s += FEXP2(base + x5 - __int_as_float(e5.y));
  s += FEXP2(base + x6 - __int_as_float(e6.y));
  s += FEXP2(base + x7 - __int_as_float(e7.y));
  for (int e = 8; e < cnt; ++e) {
    int2 pk = p[e];
    s += FEXP2(base + aloadf(&X[pk.x]) - __int_as_float(pk.y));
  }
  return s;
}

// ---------------------------------------------------------------------------
// K5 (cooperative): 16 blocks/batch (batch = blockIdx % 8 -> XCD-local),
// 1 row + 1 col per thread, U/V exchanged via relaxed sc1 atomics.
// Iteration math identical to the validated R1 kernel.
// ---------------------------------------------------------------------------
__global__ __launch_bounds__(TPB) void k_sink_coop(
    const float* __restrict__ mu, const float* __restrict__ nu,
    const int2* __restrict__ r_pk, const int* __restrict__ r_cnt,
    const int2* __restrict__ c_pk, const int* __restrict__ c_cnt,
    float* __restrict__ U_g, float* __restrict__ V_g,
    float* errS, int* arrS, int* genS, float* __restrict__ costpart) {
  const int blk = blockIdx.x;
  const int b = blk % NB, slice = blk / NB;   // %8: batch pinned to one XCD
  const int tid = threadIdx.x;
  const int r = slice * RPB + tid;
  const bool has_r = (tid < RPB) && (r < NN); // NN == NM: same geometry
  float* Ub = U_g + (size_t)b * NN;
  float* Vb = V_g + (size_t)b * NM;
  float* errb = errS + b * 32;                // per-batch cache line
  int*   arrb = arrS + b * 32;
  int*   genb = genS + b * 32;

  float u = 0.f, v = 0.f, lmu = 0.f, lnu = 0.f;
  const int2* rp = nullptr; const int2* cp = nullptr;
  int cntr = 8, cntc = 8;
  if (has_r) {
    rp = r_pk + ((size_t)b * NN + r) * CAP;
    cntr = 8 + min(r_cnt[(size_t)b * NN + r], CAP - 8);
    lmu = FLOG2(mu[(size_t)b * NN + r] + 1e-8f);
    cp = c_pk + ((size_t)b * NM + r) * CAP;
    cntc = 8 + min(c_cnt[(size_t)b * NM + r], CAP - 8);
    lnu = FLOG2(nu[(size_t)b * NM + r] + 1e-8f);
  }

  __shared__ float sred[TPB / 64];
  int wid = tid >> 6, lane = tid & 63;

  for (int it = 0; it < 100; ++it) {
    // ---- Phase A: u update ----
    float errp = 0.f;
    if (has_r) {
      float s = sprowsum(rp, cntr, u, Vb);
      float un = lmu - FLOG2(1e-8f + s) + u;
      errp = fabsf(un - u);
      u = un;
      astoref(&Ub[r], u);
    }
#pragma unroll
    for (int o = 32; o; o >>= 1) errp += __shfl_down(errp, o);
    if (lane == 0) sred[wid] = errp;
    __syncthreads();
    if (tid == 0)
      astoref(&errb[slice], sred[0] + sred[1] + sred[2] + sred[3]);
    int done = bbar(arrb, genb, errb, slice, 2 * it + 1, true);

    // ---- Phase B: v update ----
    if (has_r) {
      float s = sprowsum(cp, cntc, v, Ub);
      v = lnu - FLOG2(1e-8f + s) + v;
      astoref(&Vb[r], v);
    }
    bbar(arrb, genb, errb, slice, 2 * it + 2, false);
    if (done) break;                          // uniform across the batch
  }

  // ---- cost partial: sum pi*val over this block's rows ----
  float cs = 0.f;
  if (has_r) {
    for (int e = 0; e < cntr; ++e) {
      int2 pk = rp[e];
      float val = __int_as_float(pk.y);
      cs += FEXP2(u + aloadf(&Vb[pk.x]) - val) * val;
    }
  }
#pragma unroll
  for (int o = 32; o; o >>= 1) cs += __shfl_down(cs, o);
  if (lane == 0) sred[wid] = cs;
  __syncthreads();
  if (tid == 0) costpart[b * BPB + slice] = sred[0] + sred[1] + sred[2] + sred[3];
}

// Deterministic final reduction: fixed-order sums.
__global__ void k_final2(const float* __restrict__ costpart, float* __restrict__ out) {
  if (threadIdx.x == 0 && blockIdx.x == 0) {
    float tot = 0.f;
    for (int b = 0; b < NB; ++b) {
      float cb = 0.f;
      for (int s = 0; s < BPB; ++s) cb += costpart[b * BPB + s];
      tot += cb * UNSCALE;
    }
    out[0] = tot * (1.0f / NB);
  }
}

// ---------------------------------------------------------------------------
extern "C" void kernel_launch(void* const* d_in, const int* in_sizes, int n_in,
                              void* d_out, int out_size, void* d_ws, size_t ws_size,
                              hipStream_t stream) {
  const float* mu = (const float*)d_in[0];
  const float* nu = (const float*)d_in[1];
  const float* C  = (const float*)d_in[2];
  float* out = (float*)d_out;

  char* ws = (char*)d_ws;
  size_t off = 0;
  auto alloc = [&](size_t bytes) {
    void* p = ws + off;
    off += (bytes + 255) & ~(size_t)255;
    return p;
  };
  float* norms    = (float*)alloc(sizeof(float) * NB * NN);
  int*   rowsel   = (int*)  alloc(sizeof(int)   * NB * NN * KK);
  int*   colsel   = (int*)  alloc(sizeof(int)   * NB * NM * KK);
  int*   r_cnt    = (int*)  alloc(sizeof(int)   * NB * NN);
  int*   c_cnt    = (int*)  alloc(sizeof(int)   * NB * NM);
  int2*  r_pk     = (int2*) alloc(sizeof(int2)  * NB * NN * CAP);
  int2*  c_pk     = (int2*) alloc(sizeof(int2)  * NB * NM * CAP);
  float* U_g      = (float*)alloc(sizeof(float) * NB * NN);
  float* V_g      = (float*)alloc(sizeof(float) * NB * NM);
  float* errS     = (float*)alloc(sizeof(float) * NB * 32);
  int*   arrS     = (int*)  alloc(sizeof(int)   * NB * 32);
  int*   genS     = (int*)  alloc(sizeof(int)   * NB * 32);
  float* costpart = (float*)alloc(sizeof(float) * NB * BPB);
  (void)ws_size; (void)in_sizes; (void)n_in; (void)out_size;

  hipMemsetAsync(r_cnt, 0, sizeof(int) * NB * NN, stream);
  hipMemsetAsync(c_cnt, 0, sizeof(int) * NB * NM, stream);
  size_t span = (size_t)((char*)costpart - (char*)U_g) + sizeof(float) * NB * BPB;
  hipMemsetAsync(U_g, 0, span, stream);       // U, V, errS, arrS, genS, costpart

  hipLaunchKernelGGL(k_rowprep, dim3(NB * NN), dim3(256), 0, stream, C, norms, rowsel);
  hipLaunchKernelGGL(k_coltop, dim3((NM + COLS - 1) / COLS, NB), dim3(512), 0, stream,
                     C, norms, colsel);
  int nthreads = NB * NN * KK;
  hipLaunchKernelGGL(k_fillbase, dim3((nthreads + 255) / 256), dim3(256), 0, stream,
                     C, norms, rowsel, colsel, r_pk, c_pk);
  hipLaunchKernelGGL(k_fillextra, dim3((nthreads + 255) / 256), dim3(256), 0, stream,
                     C, norms, rowsel, colsel, r_cnt, c_cnt, r_pk, c_pk);

  void* args[] = { (void*)&mu, (void*)&nu, (void*)&r_pk, (void*)&r_cnt,
                   (void*)&c_pk, (void*)&c_cnt, (void*)&U_g, (void*)&V_g,
                   (void*)&errS, (void*)&arrS, (void*)&genS, (void*)&costpart };
  hipLaunchCooperativeKernel((const void*)k_sink_coop, dim3(NBLK), dim3(TPB),
                             args, 0, stream);

  hipLaunchKernelGGL(k_final2, dim3(1), dim3(64), 0, stream, costpart, out);
}

// Round 4
// 1759.026 us; speedup vs baseline: 4.4980x; 1.3846x over previous
//
#include <hip/hip_runtime.h>
#include <cfloat>

// Problem constants (match reference setup_inputs)
constexpr int NB = 8, NN = 3000, NM = 3000, KK = 8;
constexpr int CAP = 48;                       // per-row/col sparse capacity (padded)
constexpr int SUBS = 8, COLS = 64;            // column-topk tiling
constexpr int RPS = NN / SUBS;                // rows per sub-chunk = 375
constexpr float SCALE   = 14.426950408889634f;   // 1/(EPS*ln2), EPS=0.1
constexpr float UNSCALE = 0.06931471805599453f;  // EPS*ln2
constexpr float THRESH  = 0.1f;
constexpr int DUMMY_VAL = 0x7f7fffff;         // FLT_MAX: exp2(x - FLT_MAX) == 0

// Cooperative sinkhorn geometry: 16 blocks/batch, batch = blockIdx % 8 (XCD-local)
constexpr int BPB  = 16;
constexpr int NBLK = NB * BPB;                // 128 blocks
constexpr int TPB  = 256;
constexpr int RPB  = (NN + BPB - 1) / BPB;    // 188 rows per block

#if __has_builtin(__builtin_amdgcn_exp2f)
#define FEXP2(x) __builtin_amdgcn_exp2f(x)
#else
#define FEXP2(x) exp2f(x)
#endif
#if __has_builtin(__builtin_amdgcn_logf)
#define FLOG2(x) __builtin_amdgcn_logf(x)   // v_log_f32 = log2
#else
#define FLOG2(x) __log2f(x)
#endif

// Relaxed agent-scope atomics: plain coherence-point accesses, NO cache
// flushes (acquire/release at agent scope emit buffer_inv/buffer_wbl2 — the
// R2 barrier disaster).
__device__ __forceinline__ float aloadf(const float* p) {
  return __hip_atomic_load(p, __ATOMIC_RELAXED, __HIP_MEMORY_SCOPE_AGENT);
}
__device__ __forceinline__ void astoref(float* p, float x) {
  __hip_atomic_store(p, x, __ATOMIC_RELAXED, __HIP_MEMORY_SCOPE_AGENT);
}
__device__ __forceinline__ int aloadi(const int* p) {
  return __hip_atomic_load(p, __ATOMIC_RELAXED, __HIP_MEMORY_SCOPE_AGENT);
}
__device__ __forceinline__ void astorei(int* p, int x) {
  __hip_atomic_store(p, x, __ATOMIC_RELAXED, __HIP_MEMORY_SCOPE_AGENT);
}

// ---------------------------------------------------------------------------
// K1: per-(b,n) row: L2 norm + top-8 smallest (indices). Row staged in LDS.
// ---------------------------------------------------------------------------
__global__ __launch_bounds__(256) void k_rowprep(const float* __restrict__ C,
                                                 float* __restrict__ norms,
                                                 int* __restrict__ rowsel) {
  int bn = blockIdx.x;                       // b*NN + n
  const float* row = C + (size_t)bn * NM;
  __shared__ __align__(16) float lds[NM];
  __shared__ float rv[4];
  __shared__ int   ri[4];
  int tid = threadIdx.x;
  float sq = 0.f;
  for (int i = tid; i < NM / 4; i += 256) {
    float4 f = reinterpret_cast<const float4*>(row)[i];
    reinterpret_cast<float4*>(lds)[i] = f;
    sq += f.x * f.x + f.y * f.y + f.z * f.z + f.w * f.w;
  }
#pragma unroll
  for (int o = 32; o; o >>= 1) sq += __shfl_down(sq, o);
  int wid = tid >> 6, lane = tid & 63;
  if (lane == 0) rv[wid] = sq;
  __syncthreads();
  if (tid == 0) norms[bn] = sqrtf(rv[0] + rv[1] + rv[2] + rv[3]);
  __syncthreads();  // rv reused below

  for (int p = 0; p < KK; ++p) {
    float mv = FLT_MAX; int mi = NM;
    for (int i = tid; i < NM; i += 256) {
      float v = lds[i];
      if (v < mv) { mv = v; mi = i; }        // strided asc indices -> stable
    }
#pragma unroll
    for (int o = 32; o; o >>= 1) {
      float ov = __shfl_down(mv, o); int oi = __shfl_down(mi, o);
      if (ov < mv || (ov == mv && oi < mi)) { mv = ov; mi = oi; }
    }
    if (lane == 0) { rv[wid] = mv; ri[wid] = mi; }
    __syncthreads();
    if (tid == 0) {
      float bv = rv[0]; int bi = ri[0];
#pragma unroll
      for (int w = 1; w < 4; ++w)
        if (rv[w] < bv || (rv[w] == bv && ri[w] < bi)) { bv = rv[w]; bi = ri[w]; }
      rowsel[(size_t)bn * KK + p] = bi;
      lds[bi] = FLT_MAX;                     // exclude for next pass
    }
    __syncthreads();
  }
}

// ---------------------------------------------------------------------------
// K2: per-(b,m) column: top-8 largest of C/norm.
// ---------------------------------------------------------------------------
__global__ __launch_bounds__(512) void k_coltop(const float* __restrict__ C,
                                                const float* __restrict__ norms,
                                                int* __restrict__ colsel) {
  int b = blockIdx.y;
  int cg = blockIdx.x;
  int tid = threadIdx.x;
  int col = tid & (COLS - 1);
  int sub = tid >> 6;                         // 0..7
  int m = cg * COLS + col;
  __shared__ float inv[NN];
  __shared__ float sv[SUBS * COLS * 8];
  __shared__ int   si[SUBS * COLS * 8];
  for (int r = tid; r < NN; r += 512)
    inv[r] = 1.0f / fmaxf(norms[(size_t)b * NN + r], 1e-12f);
  __syncthreads();

  float tv[8]; int ti[8];
#pragma unroll
  for (int q = 0; q < 8; ++q) { tv[q] = -FLT_MAX; ti[q] = 0x7fffffff; }

  if (m < NM) {
    const float* base = C + ((size_t)b * NN + (size_t)sub * RPS) * NM + m;
    for (int r = 0; r < RPS; r += 5) {        // 375 = 5*75
#pragma unroll
      for (int j = 0; j < 5; ++j) {
        int rr = r + j;
        float val = base[(size_t)rr * NM] * inv[sub * RPS + rr];
        if (val > tv[7]) {                    // stable insert (ties keep earlier n)
          int idx = sub * RPS + rr;
          int pos = 8;
#pragma unroll
          for (int q = 7; q >= 0; --q) if (val > tv[q]) pos = q;
#pragma unroll
          for (int q = 7; q >= 1; --q) if (q > pos) { tv[q] = tv[q-1]; ti[q] = ti[q-1]; }
#pragma unroll
          for (int q = 0; q < 8; ++q) if (q == pos) { tv[q] = val; ti[q] = idx; }
        }
      }
    }
  }
#pragma unroll
  for (int q = 0; q < 8; ++q) { sv[tid * 8 + q] = tv[q]; si[tid * 8 + q] = ti[q]; }
  __syncthreads();

  if (tid < COLS) {
    int mcol = cg * COLS + tid;
    if (mcol < NM) {
      unsigned long long used = 0;
      for (int p = 0; p < KK; ++p) {
        float bv = -FLT_MAX; int bi = 0x7fffffff; int bq = 0;
        for (int c = 0; c < SUBS; ++c) {
#pragma unroll
          for (int q = 0; q < 8; ++q) {
            int bit = c * 8 + q;
            if ((used >> bit) & 1ull) continue;
            float v = sv[(c * COLS + tid) * 8 + q];
            int   n = si[(c * COLS + tid) * 8 + q];
            if (v > bv || (v == bv && n < bi)) { bv = v; bi = n; bq = bit; }
          }
        }
        used |= 1ull << bq;
        colsel[((size_t)b * NM + mcol) * KK + p] = bi;
      }
    }
  }
}

// ---------------------------------------------------------------------------
// K3: fill base slots (0..7) of CSR/CSC AND pad slots 8..47 with dummies
// (idx 0, val FLT_MAX -> exp2 contribution exactly 0). k_fillextra then
// overwrites dummies with real extras (sequential kernel order).
// ---------------------------------------------------------------------------
__global__ __launch_bounds__(256) void k_fillbase(const float* __restrict__ C,
    const float* __restrict__ norms, const int* __restrict__ rowsel,
    const int* __restrict__ colsel, int2* __restrict__ r_pk, int2* __restrict__ c_pk) {
  int t = blockIdx.x * 256 + threadIdx.x;
  if (t >= NB * NN * KK) return;
  int k = t % KK; int bn = t / KK;
  int b = bn / NN; int n = bn % NN;
  const int2 dummy = make_int2(0, DUMMY_VAL);
  {
    int m = rowsel[t];
    float iv = 1.0f / fmaxf(norms[bn], 1e-12f);
    float v2 = C[((size_t)b * NN + n) * NM + m] * iv * SCALE;
    r_pk[(size_t)bn * CAP + k] = make_int2(m, __float_as_int(v2));
#pragma unroll
    for (int j = 0; j < 5; ++j)
      r_pk[(size_t)bn * CAP + 8 + k * 5 + j] = dummy;   // k=0..7 covers 8..47
  }
  {
    int m2 = bn % NM;                         // reinterpret bn as b*NM+m
    int n2 = colsel[t];
    float iv = 1.0f / fmaxf(norms[(size_t)b * NN + n2], 1e-12f);
    float v2 = C[((size_t)b * NN + n2) * NM + m2] * iv * SCALE;
    c_pk[(size_t)bn * CAP + k] = make_int2(n2, __float_as_int(v2));
#pragma unroll
    for (int j = 0; j < 5; ++j)
      c_pk[(size_t)bn * CAP + 8 + k * 5 + j] = dummy;
  }
}

// ---------------------------------------------------------------------------
// K4: append non-duplicate extras (overwrite dummy slots).
// ---------------------------------------------------------------------------
__global__ __launch_bounds__(256) void k_fillextra(const float* __restrict__ C,
    const float* __restrict__ norms, const int* __restrict__ rowsel,
    const int* __restrict__ colsel, int* r_cnt, int* c_cnt,
    int2* __restrict__ r_pk, int2* __restrict__ c_pk) {
  int t = blockIdx.x * 256 + threadIdx.x;
  if (t >= NB * NM * KK) return;
  int bm = t / KK;
  int b = bm / NM; int m = bm % NM;
  {  // colsel entry (b,m,k): row n gains column m unless duplicate
    int n = colsel[t];
    const int* rs = rowsel + ((size_t)b * NN + n) * KK;
    bool dup = false;
#pragma unroll
    for (int q = 0; q < KK; ++q) dup |= (rs[q] == m);
    if (!dup) {
      int slot = 8 + atomicAdd(&r_cnt[(size_t)b * NN + n], 1);
      if (slot < CAP) {
        float iv = 1.0f / fmaxf(norms[(size_t)b * NN + n], 1e-12f);
        float v2 = C[((size_t)b * NN + n) * NM + m] * iv * SCALE;
        r_pk[((size_t)b * NN + n) * CAP + slot] = make_int2(m, __float_as_int(v2));
      }
    }
  }
  {  // rowsel entry (b,n2,k): column mm gains row n2 unless duplicate
    int n2 = m;
    int mm = rowsel[t];
    const int* cs = colsel + ((size_t)b * NM + mm) * KK;
    bool dup = false;
#pragma unroll
    for (int q = 0; q < KK; ++q) dup |= (cs[q] == n2);
    if (!dup) {
      int slot = 8 + atomicAdd(&c_cnt[(size_t)b * NM + mm], 1);
      if (slot < CAP) {
        float iv = 1.0f / fmaxf(norms[(size_t)b * NN + n2], 1e-12f);
        float v2 = C[((size_t)b * NN + n2) * NM + mm] * iv * SCALE;
        c_pk[((size_t)b * NM + mm) * CAP + slot] = make_int2(n2, __float_as_int(v2));
      }
    }
  }
}

// ---------------------------------------------------------------------------
// One-round fence-free barrier: each block stamps its own arrival slot (after
// draining its data stores via vmcnt(0)); EVERY block polls all 16 slots with
// one wave. Convergence sum computed by every block in identical fixed order
// -> deterministic, uniform decision. No leader round-trip, no cache flushes.
// ---------------------------------------------------------------------------
__device__ __forceinline__ int bbar(int* arrb, const float* errb,
                                    int slice, int stamp, bool isA) {
  __shared__ int s_done;
  __syncthreads();                     // all waves drain their stores pre-barrier
  int tid = threadIdx.x;
  if (tid < 64) {
    if (tid == 0) {
      asm volatile("s_waitcnt vmcnt(0)" ::: "memory");
      astorei(&arrb[slice], stamp);
    }
    for (;;) {
      int a = (tid < BPB) ? aloadi(&arrb[tid]) : stamp;
      if (__all(a >= stamp)) break;
      __builtin_amdgcn_s_sleep(1);
    }
    int done = 0;
    if (isA) {
      float e = (tid < BPB) ? aloadf(&errb[tid]) : 0.f;
      float tot = 0.f;
#pragma unroll
      for (int k = 0; k < BPB; ++k) tot += __shfl(e, k);   // fixed order
      done = (tot * UNSCALE < THRESH) ? 1 : 0;
    }
    if (tid == 0) s_done = done;
  }
  __syncthreads();
  return s_done;
}

// Fixed-CAP fully-unrolled sparse row sum: all 48 pk loads and all 48 V
// gathers issued concurrently (one MALL latency window), then 48 exp2.
// Dummy entries (val=FLT_MAX) contribute exp2(-huge) == 0.
__device__ __forceinline__ float sprowsum48(const int2* __restrict__ p,
                                            float base, const float* __restrict__ X) {
  int2 e[CAP];
#pragma unroll
  for (int i = 0; i < CAP; ++i) e[i] = p[i];
  float x[CAP];
#pragma unroll
  for (int i = 0; i < CAP; ++i) x[i] = aloadf(&X[e[i].x]);
  float s = 0.f;
#pragma unroll
  for (int i = 0; i < CAP; ++i) s += FEXP2(base + x[i] - __int_as_float(e[i].y));
  return s;
}

// ---------------------------------------------------------------------------
// K5 (cooperative): 16 blocks/batch (batch = blockIdx % 8 -> XCD-local),
// 1 row + 1 col per thread, U/V exchanged via relaxed agent atomics.
// ---------------------------------------------------------------------------
__global__ __launch_bounds__(TPB, 1) void k_sink_coop(
    const float* __restrict__ mu, const float* __restrict__ nu,
    const int2* __restrict__ r_pk, const int2* __restrict__ c_pk,
    float* __restrict__ U_g, float* __restrict__ V_g,
    float* errS, int* arrS, float* __restrict__ costpart) {
  const int blk = blockIdx.x;
  const int b = blk % NB, slice = blk / NB;   // %8: batch pinned to one XCD
  const int tid = threadIdx.x;
  const int r = slice * RPB + tid;
  const bool has_r = (tid < RPB) && (r < NN); // NN == NM: same geometry
  float* Ub = U_g + (size_t)b * NN;
  float* Vb = V_g + (size_t)b * NM;
  float* errb = errS + b * 32;                // per-batch cache line
  int*   arrb = arrS + b * 32;

  float u = 0.f, v = 0.f, lmu = 0.f, lnu = 0.f;
  const int2* rp = nullptr; const int2* cp = nullptr;
  if (has_r) {
    rp = r_pk + ((size_t)b * NN + r) * CAP;
    lmu = FLOG2(mu[(size_t)b * NN + r] + 1e-8f);
    cp = c_pk + ((size_t)b * NM + r) * CAP;
    lnu = FLOG2(nu[(size_t)b * NM + r] + 1e-8f);
  }

  __shared__ float sred[TPB / 64];
  int wid = tid >> 6, lane = tid & 63;

  for (int it = 0; it < 100; ++it) {
    // ---- Phase A: u update ----
    float errp = 0.f;
    if (has_r) {
      float s = sprowsum48(rp, u, Vb);
      float un = lmu - FLOG2(1e-8f + s) + u;
      errp = fabsf(un - u);
      u = un;
      astoref(&Ub[r], u);
    }
#pragma unroll
    for (int o = 32; o; o >>= 1) errp += __shfl_down(errp, o);
    if (lane == 0) sred[wid] = errp;
    __syncthreads();
    if (tid == 0)
      astoref(&errb[slice], sred[0] + sred[1] + sred[2] + sred[3]);
    int done = bbar(arrb, errb, slice, 2 * it + 1, true);

    // ---- Phase B: v update ----
    if (has_r) {
      float s = sprowsum48(cp, v, Ub);
      v = lnu - FLOG2(1e-8f + s) + v;
      astoref(&Vb[r], v);
    }
    bbar(arrb, errb, slice, 2 * it + 2, false);
    if (done) break;                          // uniform across the batch
  }

  // ---- cost partial: sum pi*val over this block's rows (dummies give 0) ----
  float cs = 0.f;
  if (has_r) {
#pragma unroll
    for (int e = 0; e < CAP; ++e) {
      int2 pk = rp[e];
      float val = __int_as_float(pk.y);
      cs += FEXP2(u + aloadf(&Vb[pk.x]) - val) * val;
    }
  }
#pragma unroll
  for (int o = 32; o; o >>= 1) cs += __shfl_down(cs, o);
  if (lane == 0) sred[wid] = cs;
  __syncthreads();
  if (tid == 0) costpart[b * BPB + slice] = sred[0] + sred[1] + sred[2] + sred[3];
}

// Deterministic final reduction: fixed-order sums.
__global__ void k_final2(const float* __restrict__ costpart, float* __restrict__ out) {
  if (threadIdx.x == 0 && blockIdx.x == 0) {
    float tot = 0.f;
    for (int b = 0; b < NB; ++b) {
      float cb = 0.f;
      for (int s = 0; s < BPB; ++s) cb += costpart[b * BPB + s];
      tot += cb * UNSCALE;
    }
    out[0] = tot * (1.0f / NB);
  }
}

// ---------------------------------------------------------------------------
extern "C" void kernel_launch(void* const* d_in, const int* in_sizes, int n_in,
                              void* d_out, int out_size, void* d_ws, size_t ws_size,
                              hipStream_t stream) {
  const float* mu = (const float*)d_in[0];
  const float* nu = (const float*)d_in[1];
  const float* C  = (const float*)d_in[2];
  float* out = (float*)d_out;

  char* ws = (char*)d_ws;
  size_t off = 0;
  auto alloc = [&](size_t bytes) {
    void* p = ws + off;
    off += (bytes + 255) & ~(size_t)255;
    return p;
  };
  float* norms    = (float*)alloc(sizeof(float) * NB * NN);
  int*   rowsel   = (int*)  alloc(sizeof(int)   * NB * NN * KK);
  int*   colsel   = (int*)  alloc(sizeof(int)   * NB * NM * KK);
  int*   r_cnt    = (int*)  alloc(sizeof(int)   * NB * NN);
  int*   c_cnt    = (int*)  alloc(sizeof(int)   * NB * NM);
  int2*  r_pk     = (int2*) alloc(sizeof(int2)  * NB * NN * CAP);
  int2*  c_pk     = (int2*) alloc(sizeof(int2)  * NB * NM * CAP);
  float* U_g      = (float*)alloc(sizeof(float) * NB * NN);
  float* V_g      = (float*)alloc(sizeof(float) * NB * NM);
  float* errS     = (float*)alloc(sizeof(float) * NB * 32);
  int*   arrS     = (int*)  alloc(sizeof(int)   * NB * 32);
  float* costpart = (float*)alloc(sizeof(float) * NB * BPB);
  (void)ws_size; (void)in_sizes; (void)n_in; (void)out_size;

  hipMemsetAsync(r_cnt, 0, sizeof(int) * NB * NN, stream);
  hipMemsetAsync(c_cnt, 0, sizeof(int) * NB * NM, stream);
  size_t span = (size_t)((char*)costpart - (char*)U_g) + sizeof(float) * NB * BPB;
  hipMemsetAsync(U_g, 0, span, stream);       // U, V, errS, arrS, costpart

  hipLaunchKernelGGL(k_rowprep, dim3(NB * NN), dim3(256), 0, stream, C, norms, rowsel);
  hipLaunchKernelGGL(k_coltop, dim3((NM + COLS - 1) / COLS, NB), dim3(512), 0, stream,
                     C, norms, colsel);
  int nthreads = NB * NN * KK;
  hipLaunchKernelGGL(k_fillbase, dim3((nthreads + 255) / 256), dim3(256), 0, stream,
                     C, norms, rowsel, colsel, r_pk, c_pk);
  hipLaunchKernelGGL(k_fillextra, dim3((nthreads + 255) / 256), dim3(256), 0, stream,
                     C, norms, rowsel, colsel, r_cnt, c_cnt, r_pk, c_pk);

  void* args[] = { (void*)&mu, (void*)&nu, (void*)&r_pk, (void*)&c_pk,
                   (void*)&U_g, (void*)&V_g, (void*)&errS, (void*)&arrS,
                   (void*)&costpart };
  hipLaunchCooperativeKernel((const void*)k_sink_coop, dim3(NBLK), dim3(TPB),
                             args, 0, stream);

  hipLaunchKernelGGL(k_final2, dim3(1), dim3(64), 0, stream, costpart, out);
}

// Round 5
// 1639.846 us; speedup vs baseline: 4.8249x; 1.0727x over previous
//
#include <hip/hip_runtime.h>
#include <cfloat>

// Problem constants (match reference setup_inputs)
constexpr int NB = 8, NN = 3000, NM = 3000, KK = 8;
constexpr int CAP = 48;                       // per-row/col sparse capacity (padded)
constexpr int SUBS = 8, COLS = 64;            // column-topk tiling
constexpr int RPS = NN / SUBS;                // rows per sub-chunk = 375
constexpr float SCALE   = 14.426950408889634f;   // 1/(EPS*ln2), EPS=0.1
constexpr float UNSCALE = 0.06931471805599453f;  // EPS*ln2
constexpr float THRESH  = 0.1f;
constexpr int DUMMY_VAL = 0x7f7fffff;         // FLT_MAX: exp2(x - FLT_MAX) == 0

// Cooperative sinkhorn geometry: 16 blocks/batch, batch = blockIdx % 8 (XCD-local)
constexpr int BPB  = 16;
constexpr int NBLK = NB * BPB;                // 128 blocks
constexpr int TPB  = 256;
constexpr int RPB  = (NN + BPB - 1) / BPB;    // 188 rows per block

#if __has_builtin(__builtin_amdgcn_exp2f)
#define FEXP2(x) __builtin_amdgcn_exp2f(x)
#else
#define FEXP2(x) exp2f(x)
#endif
#if __has_builtin(__builtin_amdgcn_logf)
#define FLOG2(x) __builtin_amdgcn_logf(x)   // v_log_f32 = log2
#else
#define FLOG2(x) __log2f(x)
#endif

// Relaxed agent-scope atomics: plain coherence-point accesses, NO cache
// flushes (acquire/release at agent scope emit buffer_inv/buffer_wbl2 — the
// R2 barrier disaster). NOTE: these bypass L0/L1 — use ONLY for cross-block
// mutable data, never for bulk gathers (the R4 lesson).
__device__ __forceinline__ float aloadf(const float* p) {
  return __hip_atomic_load(p, __ATOMIC_RELAXED, __HIP_MEMORY_SCOPE_AGENT);
}
__device__ __forceinline__ void astoref(float* p, float x) {
  __hip_atomic_store(p, x, __ATOMIC_RELAXED, __HIP_MEMORY_SCOPE_AGENT);
}
__device__ __forceinline__ int aloadi(const int* p) {
  return __hip_atomic_load(p, __ATOMIC_RELAXED, __HIP_MEMORY_SCOPE_AGENT);
}
__device__ __forceinline__ void astorei(int* p, int x) {
  __hip_atomic_store(p, x, __ATOMIC_RELAXED, __HIP_MEMORY_SCOPE_AGENT);
}

// ---------------------------------------------------------------------------
// K1: per-(b,n) row: L2 norm + top-8 smallest (indices). Row staged in LDS.
// ---------------------------------------------------------------------------
__global__ __launch_bounds__(256) void k_rowprep(const float* __restrict__ C,
                                                 float* __restrict__ norms,
                                                 int* __restrict__ rowsel) {
  int bn = blockIdx.x;                       // b*NN + n
  const float* row = C + (size_t)bn * NM;
  __shared__ __align__(16) float lds[NM];
  __shared__ float rv[4];
  __shared__ int   ri[4];
  int tid = threadIdx.x;
  float sq = 0.f;
  for (int i = tid; i < NM / 4; i += 256) {
    float4 f = reinterpret_cast<const float4*>(row)[i];
    reinterpret_cast<float4*>(lds)[i] = f;
    sq += f.x * f.x + f.y * f.y + f.z * f.z + f.w * f.w;
  }
#pragma unroll
  for (int o = 32; o; o >>= 1) sq += __shfl_down(sq, o);
  int wid = tid >> 6, lane = tid & 63;
  if (lane == 0) rv[wid] = sq;
  __syncthreads();
  if (tid == 0) norms[bn] = sqrtf(rv[0] + rv[1] + rv[2] + rv[3]);
  __syncthreads();  // rv reused below

  for (int p = 0; p < KK; ++p) {
    float mv = FLT_MAX; int mi = NM;
    for (int i = tid; i < NM; i += 256) {
      float v = lds[i];
      if (v < mv) { mv = v; mi = i; }        // strided asc indices -> stable
    }
#pragma unroll
    for (int o = 32; o; o >>= 1) {
      float ov = __shfl_down(mv, o); int oi = __shfl_down(mi, o);
      if (ov < mv || (ov == mv && oi < mi)) { mv = ov; mi = oi; }
    }
    if (lane == 0) { rv[wid] = mv; ri[wid] = mi; }
    __syncthreads();
    if (tid == 0) {
      float bv = rv[0]; int bi = ri[0];
#pragma unroll
      for (int w = 1; w < 4; ++w)
        if (rv[w] < bv || (rv[w] == bv && ri[w] < bi)) { bv = rv[w]; bi = ri[w]; }
      rowsel[(size_t)bn * KK + p] = bi;
      lds[bi] = FLT_MAX;                     // exclude for next pass
    }
    __syncthreads();
  }
}

// ---------------------------------------------------------------------------
// K2: per-(b,m) column: top-8 largest of C/norm.
// ---------------------------------------------------------------------------
__global__ __launch_bounds__(512) void k_coltop(const float* __restrict__ C,
                                                const float* __restrict__ norms,
                                                int* __restrict__ colsel) {
  int b = blockIdx.y;
  int cg = blockIdx.x;
  int tid = threadIdx.x;
  int col = tid & (COLS - 1);
  int sub = tid >> 6;                         // 0..7
  int m = cg * COLS + col;
  __shared__ float inv[NN];
  __shared__ float sv[SUBS * COLS * 8];
  __shared__ int   si[SUBS * COLS * 8];
  for (int r = tid; r < NN; r += 512)
    inv[r] = 1.0f / fmaxf(norms[(size_t)b * NN + r], 1e-12f);
  __syncthreads();

  float tv[8]; int ti[8];
#pragma unroll
  for (int q = 0; q < 8; ++q) { tv[q] = -FLT_MAX; ti[q] = 0x7fffffff; }

  if (m < NM) {
    const float* base = C + ((size_t)b * NN + (size_t)sub * RPS) * NM + m;
    for (int r = 0; r < RPS; r += 5) {        // 375 = 5*75
#pragma unroll
      for (int j = 0; j < 5; ++j) {
        int rr = r + j;
        float val = base[(size_t)rr * NM] * inv[sub * RPS + rr];
        if (val > tv[7]) {                    // stable insert (ties keep earlier n)
          int idx = sub * RPS + rr;
          int pos = 8;
#pragma unroll
          for (int q = 7; q >= 0; --q) if (val > tv[q]) pos = q;
#pragma unroll
          for (int q = 7; q >= 1; --q) if (q > pos) { tv[q] = tv[q-1]; ti[q] = ti[q-1]; }
#pragma unroll
          for (int q = 0; q < 8; ++q) if (q == pos) { tv[q] = val; ti[q] = idx; }
        }
      }
    }
  }
#pragma unroll
  for (int q = 0; q < 8; ++q) { sv[tid * 8 + q] = tv[q]; si[tid * 8 + q] = ti[q]; }
  __syncthreads();

  if (tid < COLS) {
    int mcol = cg * COLS + tid;
    if (mcol < NM) {
      unsigned long long used = 0;
      for (int p = 0; p < KK; ++p) {
        float bv = -FLT_MAX; int bi = 0x7fffffff; int bq = 0;
        for (int c = 0; c < SUBS; ++c) {
#pragma unroll
          for (int q = 0; q < 8; ++q) {
            int bit = c * 8 + q;
            if ((used >> bit) & 1ull) continue;
            float v = sv[(c * COLS + tid) * 8 + q];
            int   n = si[(c * COLS + tid) * 8 + q];
            if (v > bv || (v == bv && n < bi)) { bv = v; bi = n; bq = bit; }
          }
        }
        used |= 1ull << bq;
        colsel[((size_t)b * NM + mcol) * KK + p] = bi;
      }
    }
  }
}

// ---------------------------------------------------------------------------
// K3: fill base slots (0..7) of CSR/CSC AND pad slots 8..47 with dummies
// (idx 0, val FLT_MAX -> exp2 contribution exactly 0). k_fillextra then
// overwrites dummies with real extras (sequential kernel order).
// ---------------------------------------------------------------------------
__global__ __launch_bounds__(256) void k_fillbase(const float* __restrict__ C,
    const float* __restrict__ norms, const int* __restrict__ rowsel,
    const int* __restrict__ colsel, int2* __restrict__ r_pk, int2* __restrict__ c_pk) {
  int t = blockIdx.x * 256 + threadIdx.x;
  if (t >= NB * NN * KK) return;
  int k = t % KK; int bn = t / KK;
  int b = bn / NN; int n = bn % NN;
  const int2 dummy = make_int2(0, DUMMY_VAL);
  {
    int m = rowsel[t];
    float iv = 1.0f / fmaxf(norms[bn], 1e-12f);
    float v2 = C[((size_t)b * NN + n) * NM + m] * iv * SCALE;
    r_pk[(size_t)bn * CAP + k] = make_int2(m, __float_as_int(v2));
#pragma unroll
    for (int j = 0; j < 5; ++j)
      r_pk[(size_t)bn * CAP + 8 + k * 5 + j] = dummy;   // k=0..7 covers 8..47
  }
  {
    int m2 = bn % NM;                         // reinterpret bn as b*NM+m
    int n2 = colsel[t];
    float iv = 1.0f / fmaxf(norms[(size_t)b * NN + n2], 1e-12f);
    float v2 = C[((size_t)b * NN + n2) * NM + m2] * iv * SCALE;
    c_pk[(size_t)bn * CAP + k] = make_int2(n2, __float_as_int(v2));
#pragma unroll
    for (int j = 0; j < 5; ++j)
      c_pk[(size_t)bn * CAP + 8 + k * 5 + j] = dummy;
  }
}

// ---------------------------------------------------------------------------
// K4: append non-duplicate extras (overwrite dummy slots).
// ---------------------------------------------------------------------------
__global__ __launch_bounds__(256) void k_fillextra(const float* __restrict__ C,
    const float* __restrict__ norms, const int* __restrict__ rowsel,
    const int* __restrict__ colsel, int* r_cnt, int* c_cnt,
    int2* __restrict__ r_pk, int2* __restrict__ c_pk) {
  int t = blockIdx.x * 256 + threadIdx.x;
  if (t >= NB * NM * KK) return;
  int bm = t / KK;
  int b = bm / NM; int m = bm % NM;
  {  // colsel entry (b,m,k): row n gains column m unless duplicate
    int n = colsel[t];
    const int* rs = rowsel + ((size_t)b * NN + n) * KK;
    bool dup = false;
#pragma unroll
    for (int q = 0; q < KK; ++q) dup |= (rs[q] == m);
    if (!dup) {
      int slot = 8 + atomicAdd(&r_cnt[(size_t)b * NN + n], 1);
      if (slot < CAP) {
        float iv = 1.0f / fmaxf(norms[(size_t)b * NN + n], 1e-12f);
        float v2 = C[((size_t)b * NN + n) * NM + m] * iv * SCALE;
        r_pk[((size_t)b * NN + n) * CAP + slot] = make_int2(m, __float_as_int(v2));
      }
    }
  }
  {  // rowsel entry (b,n2,k): column mm gains row n2 unless duplicate
    int n2 = m;
    int mm = rowsel[t];
    const int* cs = colsel + ((size_t)b * NM + mm) * KK;
    bool dup = false;
#pragma unroll
    for (int q = 0; q < KK; ++q) dup |= (cs[q] == n2);
    if (!dup) {
      int slot = 8 + atomicAdd(&c_cnt[(size_t)b * NM + mm], 1);
      if (slot < CAP) {
        float iv = 1.0f / fmaxf(norms[(size_t)b * NN + n2], 1e-12f);
        float v2 = C[((size_t)b * NN + n2) * NM + mm] * iv * SCALE;
        c_pk[((size_t)b * NM + mm) * CAP + slot] = make_int2(n2, __float_as_int(v2));
      }
    }
  }
}

// ---------------------------------------------------------------------------
// One-round fence-free barrier: each block stamps its own arrival slot; every
// block polls all 16 slots with one wave. The entry __syncthreads is
// load-bearing: hipcc emits s_waitcnt vmcnt(0) per wave before s_barrier, so
// ALL waves' sc1 data stores are drained to the coherence point before tid 0
// publishes the stamp. Convergence sum computed by every block in identical
// fixed order -> deterministic, uniform decision.
// ---------------------------------------------------------------------------
__device__ __forceinline__ int bbar(int* arrb, const float* errb,
                                    int slice, int stamp, bool isA) {
  __shared__ int s_done;
  __syncthreads();
  int tid = threadIdx.x;
  if (tid < 64) {
    if (tid == 0) {
      asm volatile("s_waitcnt vmcnt(0)" ::: "memory");
      astorei(&arrb[slice], stamp);
    }
    for (;;) {
      int a = (tid < BPB) ? aloadi(&arrb[tid]) : stamp;
      if (__all(a >= stamp)) break;
      __builtin_amdgcn_s_sleep(1);
    }
    int done = 0;
    if (isA) {
      float e = (tid < BPB) ? aloadf(&errb[tid]) : 0.f;
      float tot = 0.f;
#pragma unroll
      for (int k = 0; k < BPB; ++k) tot += __shfl(e, k);   // fixed order
      done = (tot * UNSCALE < THRESH) ? 1 : 0;
    }
    if (tid == 0) s_done = done;
  }
  __syncthreads();
  return s_done;
}

// ---------------------------------------------------------------------------
// K5 (cooperative): 16 blocks/batch (batch = blockIdx % 8 -> XCD-local).
// Sparse entries live in REGISTERS (48 vals + 24 packed idx pairs per matrix,
// loaded once). Per phase: stage fresh U/V into LDS (coalesced sc1 loads),
// then 48 LDS gathers + exp2 per thread. Cross-block exchange via relaxed
// agent atomics only for the 12 KB potential vectors + barrier words.
// ---------------------------------------------------------------------------
__global__ __launch_bounds__(TPB, 1) void k_sink_coop(
    const float* __restrict__ mu, const float* __restrict__ nu,
    const int2* __restrict__ r_pk, const int2* __restrict__ c_pk,
    float* __restrict__ U_g, float* __restrict__ V_g,
    float* errS, int* arrS, float* __restrict__ costpart) {
  const int blk = blockIdx.x;
  const int b = blk % NB, slice = blk / NB;   // %8: batch pinned to one XCD
  const int tid = threadIdx.x;
  const int r = slice * RPB + tid;
  const bool has_r = (tid < RPB) && (r < NN); // NN == NM: same geometry
  float* Ub = U_g + (size_t)b * NN;
  float* Vb = V_g + (size_t)b * NM;
  float* errb = errS + b * 32;                // per-batch cache line
  int*   arrb = arrS + b * 32;

  // wave-resident sparse entries (persistent VGPRs; 1 block/CU, 1 wave/SIMD
  // -> up to 512 VGPR budget, ~220 used)
  float rval[CAP], cval[CAP];
  unsigned ridx[CAP / 2], cidx[CAP / 2];
  float u = 0.f, vv = 0.f, lmu = 0.f, lnu = 0.f;
  if (has_r) {
    const int2* rp = r_pk + ((size_t)b * NN + r) * CAP;
    const int2* cp = c_pk + ((size_t)b * NM + r) * CAP;
#pragma unroll
    for (int i = 0; i < CAP; i += 2) {
      int2 e0 = rp[i], e1 = rp[i + 1];
      rval[i] = __int_as_float(e0.y); rval[i + 1] = __int_as_float(e1.y);
      ridx[i / 2] = (unsigned)e0.x | ((unsigned)e1.x << 16);
      int2 f0 = cp[i], f1 = cp[i + 1];
      cval[i] = __int_as_float(f0.y); cval[i + 1] = __int_as_float(f1.y);
      cidx[i / 2] = (unsigned)f0.x | ((unsigned)f1.x << 16);
    }
    lmu = FLOG2(mu[(size_t)b * NN + r] + 1e-8f);
    lnu = FLOG2(nu[(size_t)b * NM + r] + 1e-8f);
  } else {
#pragma unroll
    for (int i = 0; i < CAP; ++i) { rval[i] = __int_as_float(DUMMY_VAL); cval[i] = __int_as_float(DUMMY_VAL); }
#pragma unroll
    for (int i = 0; i < CAP / 2; ++i) { ridx[i] = 0; cidx[i] = 0; }
  }

  __shared__ float XL[NN];                    // staged U or V (12 KB, reused)
  __shared__ float sred[TPB / 64];
  int wid = tid >> 6, lane = tid & 63;
  int done = 0;

  for (int it = 0; it < 100; ++it) {
    // ---- Phase A: stage V -> XL, then u update ----
    for (int i = tid; i < NN; i += TPB) XL[i] = aloadf(&Vb[i]);
    __syncthreads();
    float errp = 0.f;
    if (has_r) {
      float s = 0.f;
#pragma unroll
      for (int i = 0; i < CAP; ++i) {
        int ix = (ridx[i >> 1] >> ((i & 1) * 16)) & 0xFFFF;
        s += FEXP2(u + XL[ix] - rval[i]);
      }
      float un = lmu - FLOG2(1e-8f + s) + u;
      errp = fabsf(un - u);
      u = un;
      astoref(&Ub[r], u);
    }
#pragma unroll
    for (int o = 32; o; o >>= 1) errp += __shfl_down(errp, o);
    if (lane == 0) sred[wid] = errp;
    __syncthreads();
    if (tid == 0)
      astoref(&errb[slice], sred[0] + sred[1] + sred[2] + sred[3]);
    done = bbar(arrb, errb, slice, 2 * it + 1, true);

    // ---- Phase B: stage U -> XL, then v update ----
    for (int i = tid; i < NN; i += TPB) XL[i] = aloadf(&Ub[i]);
    __syncthreads();
    if (has_r) {
      float s = 0.f;
#pragma unroll
      for (int i = 0; i < CAP; ++i) {
        int ix = (cidx[i >> 1] >> ((i & 1) * 16)) & 0xFFFF;
        s += FEXP2(vv + XL[ix] - cval[i]);
      }
      vv = lnu - FLOG2(1e-8f + s) + vv;
      astoref(&Vb[r], vv);
    }
    bbar(arrb, errb, slice, 2 * it + 2, false);
    if (done) break;                          // uniform across the batch
  }

  // ---- cost partial: stage final V, then sum pi*val (dummies give 0) ----
  for (int i = tid; i < NN; i += TPB) XL[i] = aloadf(&Vb[i]);
  __syncthreads();
  float cs = 0.f;
  if (has_r) {
#pragma unroll
    for (int i = 0; i < CAP; ++i) {
      int ix = (ridx[i >> 1] >> ((i & 1) * 16)) & 0xFFFF;
      float val = rval[i];
      cs += FEXP2(u + XL[ix] - val) * val;
    }
  }
#pragma unroll
  for (int o = 32; o; o >>= 1) cs += __shfl_down(cs, o);
  if (lane == 0) sred[wid] = cs;
  __syncthreads();
  if (tid == 0) costpart[b * BPB + slice] = sred[0] + sred[1] + sred[2] + sred[3];
}

// Deterministic final reduction: fixed-order sums.
__global__ void k_final2(const float* __restrict__ costpart, float* __restrict__ out) {
  if (threadIdx.x == 0 && blockIdx.x == 0) {
    float tot = 0.f;
    for (int b = 0; b < NB; ++b) {
      float cb = 0.f;
      for (int s = 0; s < BPB; ++s) cb += costpart[b * BPB + s];
      tot += cb * UNSCALE;
    }
    out[0] = tot * (1.0f / NB);
  }
}

// ---------------------------------------------------------------------------
extern "C" void kernel_launch(void* const* d_in, const int* in_sizes, int n_in,
                              void* d_out, int out_size, void* d_ws, size_t ws_size,
                              hipStream_t stream) {
  const float* mu = (const float*)d_in[0];
  const float* nu = (const float*)d_in[1];
  const float* C  = (const float*)d_in[2];
  float* out = (float*)d_out;

  char* ws = (char*)d_ws;
  size_t off = 0;
  auto alloc = [&](size_t bytes) {
    void* p = ws + off;
    off += (bytes + 255) & ~(size_t)255;
    return p;
  };
  float* norms    = (float*)alloc(sizeof(float) * NB * NN);
  int*   rowsel   = (int*)  alloc(sizeof(int)   * NB * NN * KK);
  int*   colsel   = (int*)  alloc(sizeof(int)   * NB * NM * KK);
  int*   r_cnt    = (int*)  alloc(sizeof(int)   * NB * NN);
  int*   c_cnt    = (int*)  alloc(sizeof(int)   * NB * NM);
  int2*  r_pk     = (int2*) alloc(sizeof(int2)  * NB * NN * CAP);
  int2*  c_pk     = (int2*) alloc(sizeof(int2)  * NB * NM * CAP);
  float* U_g      = (float*)alloc(sizeof(float) * NB * NN);
  float* V_g      = (float*)alloc(sizeof(float) * NB * NM);
  float* errS     = (float*)alloc(sizeof(float) * NB * 32);
  int*   arrS     = (int*)  alloc(sizeof(int)   * NB * 32);
  float* costpart = (float*)alloc(sizeof(float) * NB * BPB);
  (void)ws_size; (void)in_sizes; (void)n_in; (void)out_size;

  // One memset covers r_cnt..costpart (r_pk/c_pk are fully overwritten by
  // k_fillbase, so zeroing them is harmless; saves two dispatches).
  size_t span = (size_t)((char*)costpart - (char*)r_cnt)
              + ((sizeof(float) * NB * BPB + 255) & ~(size_t)255);
  hipMemsetAsync(r_cnt, 0, span, stream);

  hipLaunchKernelGGL(k_rowprep, dim3(NB * NN), dim3(256), 0, stream, C, norms, rowsel);
  hipLaunchKernelGGL(k_coltop, dim3((NM + COLS - 1) / COLS, NB), dim3(512), 0, stream,
                     C, norms, colsel);
  int nthreads = NB * NN * KK;
  hipLaunchKernelGGL(k_fillbase, dim3((nthreads + 255) / 256), dim3(256), 0, stream,
                     C, norms, rowsel, colsel, r_pk, c_pk);
  hipLaunchKernelGGL(k_fillextra, dim3((nthreads + 255) / 256), dim3(256), 0, stream,
                     C, norms, rowsel, colsel, r_cnt, c_cnt, r_pk, c_pk);

  void* args[] = { (void*)&mu, (void*)&nu, (void*)&r_pk, (void*)&c_pk,
                   (void*)&U_g, (void*)&V_g, (void*)&errS, (void*)&arrS,
                   (void*)&costpart };
  hipLaunchCooperativeKernel((const void*)k_sink_coop, dim3(NBLK), dim3(TPB),
                             args, 0, stream);

  hipLaunchKernelGGL(k_final2, dim3(1), dim3(64), 0, stream, costpart, out);
}

// Round 6
// 1362.910 us; speedup vs baseline: 5.8053x; 1.2032x over previous
//
#include <hip/hip_runtime.h>
#include <cfloat>

// Problem constants (match reference setup_inputs)
constexpr int NB = 8, NN = 3000, NM = 3000, KK = 8;
constexpr int CAP = 48;                       // per-row/col sparse capacity (padded)
constexpr int SUBS = 8, COLS = 64;            // column-topk tiling
constexpr int RPS = NN / SUBS;                // rows per sub-chunk = 375
constexpr float SCALE   = 14.426950408889634f;   // 1/(EPS*ln2), EPS=0.1
constexpr float UNSCALE = 0.06931471805599453f;  // EPS*ln2
constexpr float THRESH  = 0.1f;
constexpr int DUMMY_VAL = 0x7f7fffff;         // FLT_MAX: exp2(x - FLT_MAX) == 0

// Sinkhorn geometry: 8 blocks/batch, wave w <-> producer-slice w (1:1)
constexpr int BPB  = 8;
constexpr int NBLK = NB * BPB;                // 64 blocks
constexpr int TPB  = 512;                     // 8 waves
constexpr int RPB  = NN / BPB;                // 375 rows per block

#if __has_builtin(__builtin_amdgcn_exp2f)
#define FEXP2(x) __builtin_amdgcn_exp2f(x)
#else
#define FEXP2(x) exp2f(x)
#endif
#if __has_builtin(__builtin_amdgcn_logf)
#define FLOG2(x) __builtin_amdgcn_logf(x)   // v_log_f32 = log2
#else
#define FLOG2(x) __log2f(x)
#endif

// Relaxed agent-scope atomics: plain coherence-point accesses, NO cache
// flushes (acquire/release at agent scope emit buffer_inv/buffer_wbl2 — the
// R2 disaster). Bypass L0/L1 — used ONLY for cross-block mutable data.
__device__ __forceinline__ float aloadf(const float* p) {
  return __hip_atomic_load(p, __ATOMIC_RELAXED, __HIP_MEMORY_SCOPE_AGENT);
}
__device__ __forceinline__ void astoref(float* p, float x) {
  __hip_atomic_store(p, x, __ATOMIC_RELAXED, __HIP_MEMORY_SCOPE_AGENT);
}
__device__ __forceinline__ int aloadi(const int* p) {
  return __hip_atomic_load(p, __ATOMIC_RELAXED, __HIP_MEMORY_SCOPE_AGENT);
}
__device__ __forceinline__ void astorei(int* p, int x) {
  __hip_atomic_store(p, x, __ATOMIC_RELAXED, __HIP_MEMORY_SCOPE_AGENT);
}

// ---------------------------------------------------------------------------
// K1: per-(b,n) row: L2 norm + top-8 smallest. Single pass: per-thread
// register top-8 during the global read (stable: ascending index order,
// strict <), then one-wave register-cached tournament merge.
// ---------------------------------------------------------------------------
__global__ __launch_bounds__(256) void k_rowprep(const float* __restrict__ C,
                                                 float* __restrict__ norms,
                                                 int* __restrict__ rowsel) {
  int bn = blockIdx.x;                       // b*NN + n
  const float4* row4 = reinterpret_cast<const float4*>(C + (size_t)bn * NM);
  int tid = threadIdx.x;
  __shared__ float sv[256 * 8];
  __shared__ int   si[256 * 8];
  __shared__ float rv[4];

  float tv[8]; int ti[8];
#pragma unroll
  for (int q = 0; q < 8; ++q) { tv[q] = FLT_MAX; ti[q] = 0x7fffffff; }
  float sq = 0.f;
#pragma unroll
  for (int c = 0; c < 3; ++c) {
    int i = tid + c * 256;
    if (i < NM / 4) {                        // 750 float4 per row
      float4 f = row4[i];
      sq += f.x * f.x + f.y * f.y + f.z * f.z + f.w * f.w;
      float e[4] = { f.x, f.y, f.z, f.w };
#pragma unroll
      for (int j = 0; j < 4; ++j) {
        float v = e[j];
        if (v < tv[7]) {                     // stable: ties keep earlier idx
          int idx = 4 * i + j;
          int pos = 8;
#pragma unroll
          for (int q = 7; q >= 0; --q) if (v < tv[q]) pos = q;
#pragma unroll
          for (int q = 7; q >= 1; --q) if (q > pos) { tv[q] = tv[q-1]; ti[q] = ti[q-1]; }
#pragma unroll
          for (int q = 0; q < 8; ++q) if (q == pos) { tv[q] = v; ti[q] = idx; }
        }
      }
    }
  }
#pragma unroll
  for (int q = 0; q < 8; ++q) { sv[tid * 8 + q] = tv[q]; si[tid * 8 + q] = ti[q]; }
  // norm reduction
#pragma unroll
  for (int o = 32; o; o >>= 1) sq += __shfl_down(sq, o);
  int wid = tid >> 6, lane = tid & 63;
  if (lane == 0) rv[wid] = sq;
  __syncthreads();
  if (tid == 0) norms[bn] = sqrtf(rv[0] + rv[1] + rv[2] + rv[3]);

  // merge on wave 0: each lane caches 4 threads' candidates (32) in regs
  if (tid < 64) {
    float cv[32]; int ci[32];
#pragma unroll
    for (int c = 0; c < 4; ++c)
#pragma unroll
      for (int q = 0; q < 8; ++q) {
        cv[c * 8 + q] = sv[(tid + c * 64) * 8 + q];
        ci[c * 8 + q] = si[(tid + c * 64) * 8 + q];
      }
    for (int p = 0; p < KK; ++p) {
      float bv = FLT_MAX; int bi = 0x7fffffff;
#pragma unroll
      for (int k = 0; k < 32; ++k)
        if (cv[k] < bv || (cv[k] == bv && ci[k] < bi)) { bv = cv[k]; bi = ci[k]; }
#pragma unroll
      for (int o = 32; o; o >>= 1) {
        float ov = __shfl_xor(bv, o); int oi = __shfl_xor(bi, o);
        if (ov < bv || (ov == bv && oi < bi)) { bv = ov; bi = oi; }
      }
      if (tid == 0) rowsel[(size_t)bn * KK + p] = bi;
#pragma unroll
      for (int k = 0; k < 32; ++k)
        if (ci[k] == bi) { cv[k] = FLT_MAX; ci[k] = 0x7fffffff; }  // col idx unique per row
    }
  }
}

// ---------------------------------------------------------------------------
// K2: per-(b,m) column: top-8 largest of C/norm.
// ---------------------------------------------------------------------------
__global__ __launch_bounds__(512) void k_coltop(const float* __restrict__ C,
                                                const float* __restrict__ norms,
                                                int* __restrict__ colsel) {
  int b = blockIdx.y;
  int cg = blockIdx.x;
  int tid = threadIdx.x;
  int col = tid & (COLS - 1);
  int sub = tid >> 6;                         // 0..7
  int m = cg * COLS + col;
  __shared__ float inv[NN];
  __shared__ float sv[SUBS * COLS * 8];
  __shared__ int   si[SUBS * COLS * 8];
  for (int r = tid; r < NN; r += 512)
    inv[r] = 1.0f / fmaxf(norms[(size_t)b * NN + r], 1e-12f);
  __syncthreads();

  float tv[8]; int ti[8];
#pragma unroll
  for (int q = 0; q < 8; ++q) { tv[q] = -FLT_MAX; ti[q] = 0x7fffffff; }

  if (m < NM) {
    const float* base = C + ((size_t)b * NN + (size_t)sub * RPS) * NM + m;
    for (int r = 0; r < RPS; r += 5) {        // 375 = 5*75
#pragma unroll
      for (int j = 0; j < 5; ++j) {
        int rr = r + j;
        float val = base[(size_t)rr * NM] * inv[sub * RPS + rr];
        if (val > tv[7]) {                    // stable insert (ties keep earlier n)
          int idx = sub * RPS + rr;
          int pos = 8;
#pragma unroll
          for (int q = 7; q >= 0; --q) if (val > tv[q]) pos = q;
#pragma unroll
          for (int q = 7; q >= 1; --q) if (q > pos) { tv[q] = tv[q-1]; ti[q] = ti[q-1]; }
#pragma unroll
          for (int q = 0; q < 8; ++q) if (q == pos) { tv[q] = val; ti[q] = idx; }
        }
      }
    }
  }
#pragma unroll
  for (int q = 0; q < 8; ++q) { sv[tid * 8 + q] = tv[q]; si[tid * 8 + q] = ti[q]; }
  __syncthreads();

  if (tid < COLS) {
    int mcol = cg * COLS + tid;
    if (mcol < NM) {
      unsigned long long used = 0;
      for (int p = 0; p < KK; ++p) {
        float bv = -FLT_MAX; int bi = 0x7fffffff; int bq = 0;
        for (int c = 0; c < SUBS; ++c) {
#pragma unroll
          for (int q = 0; q < 8; ++q) {
            int bit = c * 8 + q;
            if ((used >> bit) & 1ull) continue;
            float v = sv[(c * COLS + tid) * 8 + q];
            int   n = si[(c * COLS + tid) * 8 + q];
            if (v > bv || (v == bv && n < bi)) { bv = v; bi = n; bq = bit; }
          }
        }
        used |= 1ull << bq;
        colsel[((size_t)b * NM + mcol) * KK + p] = bi;
      }
    }
  }
}

// ---------------------------------------------------------------------------
// K3: fill base slots (0..7) of CSR/CSC AND pad slots 8..47 with dummies.
// ---------------------------------------------------------------------------
__global__ __launch_bounds__(256) void k_fillbase(const float* __restrict__ C,
    const float* __restrict__ norms, const int* __restrict__ rowsel,
    const int* __restrict__ colsel, int2* __restrict__ r_pk, int2* __restrict__ c_pk) {
  int t = blockIdx.x * 256 + threadIdx.x;
  if (t >= NB * NN * KK) return;
  int k = t % KK; int bn = t / KK;
  int b = bn / NN; int n = bn % NN;
  const int2 dummy = make_int2(0, DUMMY_VAL);
  {
    int m = rowsel[t];
    float iv = 1.0f / fmaxf(norms[bn], 1e-12f);
    float v2 = C[((size_t)b * NN + n) * NM + m] * iv * SCALE;
    r_pk[(size_t)bn * CAP + k] = make_int2(m, __float_as_int(v2));
#pragma unroll
    for (int j = 0; j < 5; ++j)
      r_pk[(size_t)bn * CAP + 8 + k * 5 + j] = dummy;   // k=0..7 covers 8..47
  }
  {
    int m2 = bn % NM;                         // reinterpret bn as b*NM+m
    int n2 = colsel[t];
    float iv = 1.0f / fmaxf(norms[(size_t)b * NN + n2], 1e-12f);
    float v2 = C[((size_t)b * NN + n2) * NM + m2] * iv * SCALE;
    c_pk[(size_t)bn * CAP + k] = make_int2(n2, __float_as_int(v2));
#pragma unroll
    for (int j = 0; j < 5; ++j)
      c_pk[(size_t)bn * CAP + 8 + k * 5 + j] = dummy;
  }
}

// ---------------------------------------------------------------------------
// K4: append non-duplicate extras (overwrite dummy slots).
// ---------------------------------------------------------------------------
__global__ __launch_bounds__(256) void k_fillextra(const float* __restrict__ C,
    const float* __restrict__ norms, const int* __restrict__ rowsel,
    const int* __restrict__ colsel, int* r_cnt, int* c_cnt,
    int2* __restrict__ r_pk, int2* __restrict__ c_pk) {
  int t = blockIdx.x * 256 + threadIdx.x;
  if (t >= NB * NM * KK) return;
  int bm = t / KK;
  int b = bm / NM; int m = bm % NM;
  {  // colsel entry (b,m,k): row n gains column m unless duplicate
    int n = colsel[t];
    const int* rs = rowsel + ((size_t)b * NN + n) * KK;
    bool dup = false;
#pragma unroll
    for (int q = 0; q < KK; ++q) dup |= (rs[q] == m);
    if (!dup) {
      int slot = 8 + atomicAdd(&r_cnt[(size_t)b * NN + n], 1);
      if (slot < CAP) {
        float iv = 1.0f / fmaxf(norms[(size_t)b * NN + n], 1e-12f);
        float v2 = C[((size_t)b * NN + n) * NM + m] * iv * SCALE;
        r_pk[((size_t)b * NN + n) * CAP + slot] = make_int2(m, __float_as_int(v2));
      }
    }
  }
  {  // rowsel entry (b,n2,k): column mm gains row n2 unless duplicate
    int n2 = m;
    int mm = rowsel[t];
    const int* cs = colsel + ((size_t)b * NM + mm) * KK;
    bool dup = false;
#pragma unroll
    for (int q = 0; q < KK; ++q) dup |= (cs[q] == n2);
    if (!dup) {
      int slot = 8 + atomicAdd(&c_cnt[(size_t)b * NM + mm], 1);
      if (slot < CAP) {
        float iv = 1.0f / fmaxf(norms[(size_t)b * NN + n2], 1e-12f);
        float v2 = C[((size_t)b * NN + n2) * NM + mm] * iv * SCALE;
        c_pk[((size_t)b * NM + mm) * CAP + slot] = make_int2(n2, __float_as_int(v2));
      }
    }
  }
}

// ---------------------------------------------------------------------------
// K5: pull-as-ready sparse Sinkhorn. 8 blocks/batch; wave w pulls producer
// w's slice as soon as its stamp shows. Published U/V parity double-buffered
// by iteration (reuse distance 2 => no overwrite race: A(it+2) overwriting
// Upub[it&1] transitively requires every consumer to have finished B(it)).
// Error partials ride the U stamps; every block sums the same 8 published
// floats in fixed order -> deterministic uniform break (freeze semantics
// identical to the validated R1 kernel).
// Stamp protocol: A(it) publishes U+err, stampU=it+1. B(it) needs stampU>=it+1,
// publishes V, stampV=it+1. A(it>=1) needs stampV>=it. Store-release via
// __syncthreads (per-wave vmcnt(0) drain) + tid0 vmcnt(0) before stamping.
// ---------------------------------------------------------------------------
__global__ __launch_bounds__(TPB, 1) void k_sink_coop(
    const float* __restrict__ mu, const float* __restrict__ nu,
    const int2* __restrict__ r_pk, const int2* __restrict__ c_pk,
    float* __restrict__ Upub, float* __restrict__ Vpub,
    int* stU, int* stV, float* errW, float* __restrict__ costpart) {
  const int blk = blockIdx.x;
  const int b = blk % NB, slice = blk / NB;   // %8: batch pinned per XCD (heuristic)
  const int tid = threadIdx.x;
  const int w = tid >> 6, lane = tid & 63;
  const int r = slice * RPB + tid;
  const bool has_r = (tid < RPB);             // NN == NM: same geometry

  // wave-resident sparse entries (persistent VGPRs; 2 waves/SIMD -> 256 budget)
  float rval[CAP], cval[CAP];
  unsigned ridx[CAP / 2], cidx[CAP / 2];
  float u = 0.f, vv = 0.f, lmu = 0.f, lnu = 0.f;
  if (has_r) {
    const int2* rp = r_pk + ((size_t)b * NN + r) * CAP;
    const int2* cp = c_pk + ((size_t)b * NM + r) * CAP;
#pragma unroll
    for (int i = 0; i < CAP; i += 2) {
      int2 e0 = rp[i], e1 = rp[i + 1];
      rval[i] = __int_as_float(e0.y); rval[i + 1] = __int_as_float(e1.y);
      ridx[i / 2] = (unsigned)e0.x | ((unsigned)e1.x << 16);
      int2 f0 = cp[i], f1 = cp[i + 1];
      cval[i] = __int_as_float(f0.y); cval[i + 1] = __int_as_float(f1.y);
      cidx[i / 2] = (unsigned)f0.x | ((unsigned)f1.x << 16);
    }
    lmu = FLOG2(mu[(size_t)b * NN + r] + 1e-8f);
    lnu = FLOG2(nu[(size_t)b * NM + r] + 1e-8f);
  }

  __shared__ float XL[NN];                    // staged U or V (12 KB)
  __shared__ float sred[TPB / 64];
  __shared__ float errl[BPB];
  int*   stUb = stU + b * BPB * 16;
  int*   stVb = stV + b * BPB * 16;
  int itf = 0;
  bool done = false;

  for (int it = 0; it < 100; ++it) {
    // ---- stage-A: V(it-1) (zeros at it==0), wave w pulls producer w ----
    if (it == 0) {
      for (int i = tid; i < NN; i += TPB) XL[i] = 0.f;
    } else {
      const float* src = Vpub + (size_t)((it - 1) & 1) * (NB * NN) + (size_t)b * NN;
      const int* st = stVb + w * 16;
      while (aloadi(st) < it) __builtin_amdgcn_s_sleep(1);   // wave-uniform
      for (int i = lane; i < RPB; i += 64)
        XL[w * RPB + i] = aloadf(&src[w * RPB + i]);
    }
    __syncthreads();

    // ---- compute-A: u update, publish U + err ----
    float errp = 0.f;
    if (has_r) {
      float s = 0.f;
#pragma unroll
      for (int i = 0; i < CAP; ++i) {
        int ix = (ridx[i >> 1] >> ((i & 1) * 16)) & 0xFFFF;
        s += FEXP2(u + XL[ix] - rval[i]);
      }
      float un = lmu - FLOG2(1e-8f + s) + u;
      errp = fabsf(un - u);
      u = un;
      astoref(&Upub[(size_t)(it & 1) * (NB * NN) + (size_t)b * NN + r], u);
    }
#pragma unroll
    for (int o = 32; o; o >>= 1) errp += __shfl_down(errp, o);
    if (lane == 0) sred[w] = errp;
    __syncthreads();                          // drains ALL waves' U stores too
    if (tid == 0) {
      float e = sred[0] + sred[1] + sred[2] + sred[3]
              + sred[4] + sred[5] + sred[6] + sred[7];
      astoref(&errW[(size_t)((it & 1) * NB + b) * BPB * 16 + slice * 16], e);
      asm volatile("s_waitcnt vmcnt(0)" ::: "memory");
      astorei(&stUb[slice * 16], it + 1);
    }

    // ---- stage-B: U(it), wave w pulls producer w + its err word ----
    {
      const float* src = Upub + (size_t)(it & 1) * (NB * NN) + (size_t)b * NN;
      const int* st = stUb + w * 16;
      while (aloadi(st) < it + 1) __builtin_amdgcn_s_sleep(1);
      for (int i = lane; i < RPB; i += 64)
        XL[w * RPB + i] = aloadf(&src[w * RPB + i]);
      if (lane == 0)
        errl[w] = aloadf(&errW[(size_t)((it & 1) * NB + b) * BPB * 16 + w * 16]);
    }
    __syncthreads();

    // ---- compute-B: v update, publish V; uniform done decision ----
    float errtot = errl[0] + errl[1] + errl[2] + errl[3]
                 + errl[4] + errl[5] + errl[6] + errl[7];   // fixed order
    done = (errtot * UNSCALE < THRESH);
    if (has_r) {
      float s = 0.f;
#pragma unroll
      for (int i = 0; i < CAP; ++i) {
        int ix = (cidx[i >> 1] >> ((i & 1) * 16)) & 0xFFFF;
        s += FEXP2(vv + XL[ix] - cval[i]);
      }
      vv = lnu - FLOG2(1e-8f + s) + vv;
      astoref(&Vpub[(size_t)(it & 1) * (NB * NN) + (size_t)b * NN + r], vv);
    }
    __syncthreads();                          // drain all V stores
    if (tid == 0) astorei(&stVb[slice * 16], it + 1);
    itf = it;
    if (done) break;                          // uniform across the batch
  }

  // ---- epilogue: stage final V(itf), cost partial over own rows ----
  {
    const float* src = Vpub + (size_t)(itf & 1) * (NB * NN) + (size_t)b * NN;
    const int* st = stVb + w * 16;
    while (aloadi(st) < itf + 1) __builtin_amdgcn_s_sleep(1);
    for (int i = lane; i < RPB; i += 64)
      XL[w * RPB + i] = aloadf(&src[w * RPB + i]);
  }
  __syncthreads();
  float cs = 0.f;
  if (has_r) {
#pragma unroll
    for (int i = 0; i < CAP; ++i) {
      int ix = (ridx[i >> 1] >> ((i & 1) * 16)) & 0xFFFF;
      float val = rval[i];
      cs += FEXP2(u + XL[ix] - val) * val;    // dummies give 0
    }
  }
#pragma unroll
  for (int o = 32; o; o >>= 1) cs += __shfl_down(cs, o);
  if (lane == 0) sred[w] = cs;
  __syncthreads();
  if (tid == 0)
    costpart[b * BPB + slice] = sred[0] + sred[1] + sred[2] + sred[3]
                              + sred[4] + sred[5] + sred[6] + sred[7];
}

// Deterministic final reduction: fixed-order sums.
__global__ void k_final2(const float* __restrict__ costpart, float* __restrict__ out) {
  if (threadIdx.x == 0 && blockIdx.x == 0) {
    float tot = 0.f;
    for (int b = 0; b < NB; ++b) {
      float cb = 0.f;
      for (int s = 0; s < BPB; ++s) cb += costpart[b * BPB + s];
      tot += cb * UNSCALE;
    }
    out[0] = tot * (1.0f / NB);
  }
}

// ---------------------------------------------------------------------------
extern "C" void kernel_launch(void* const* d_in, const int* in_sizes, int n_in,
                              void* d_out, int out_size, void* d_ws, size_t ws_size,
                              hipStream_t stream) {
  const float* mu = (const float*)d_in[0];
  const float* nu = (const float*)d_in[1];
  const float* C  = (const float*)d_in[2];
  float* out = (float*)d_out;

  char* ws = (char*)d_ws;
  size_t off = 0;
  auto alloc = [&](size_t bytes) {
    void* p = ws + off;
    off += (bytes + 255) & ~(size_t)255;
    return p;
  };
  float* norms    = (float*)alloc(sizeof(float) * NB * NN);
  int*   rowsel   = (int*)  alloc(sizeof(int)   * NB * NN * KK);
  int*   colsel   = (int*)  alloc(sizeof(int)   * NB * NM * KK);
  int2*  r_pk     = (int2*) alloc(sizeof(int2)  * NB * NN * CAP);
  int2*  c_pk     = (int2*) alloc(sizeof(int2)  * NB * NM * CAP);
  float* Upub     = (float*)alloc(sizeof(float) * 2 * NB * NN);  // parity dbuf
  float* Vpub     = (float*)alloc(sizeof(float) * 2 * NB * NM);
  // ---- zeroed region starts here ----
  int*   r_cnt    = (int*)  alloc(sizeof(int)   * NB * NN);
  int*   c_cnt    = (int*)  alloc(sizeof(int)   * NB * NM);
  int*   stU      = (int*)  alloc(sizeof(int)   * NB * BPB * 16);
  int*   stV      = (int*)  alloc(sizeof(int)   * NB * BPB * 16);
  float* errW     = (float*)alloc(sizeof(float) * 2 * NB * BPB * 16);
  float* costpart = (float*)alloc(sizeof(float) * NB * BPB);
  (void)ws_size; (void)in_sizes; (void)n_in; (void)out_size;

  size_t span = (size_t)((char*)costpart - (char*)r_cnt)
              + ((sizeof(float) * NB * BPB + 255) & ~(size_t)255);
  hipMemsetAsync(r_cnt, 0, span, stream);     // r_cnt..costpart (stamps -> 0)

  hipLaunchKernelGGL(k_rowprep, dim3(NB * NN), dim3(256), 0, stream, C, norms, rowsel);
  hipLaunchKernelGGL(k_coltop, dim3((NM + COLS - 1) / COLS, NB), dim3(512), 0, stream,
                     C, norms, colsel);
  int nthreads = NB * NN * KK;
  hipLaunchKernelGGL(k_fillbase, dim3((nthreads + 255) / 256), dim3(256), 0, stream,
                     C, norms, rowsel, colsel, r_pk, c_pk);
  hipLaunchKernelGGL(k_fillextra, dim3((nthreads + 255) / 256), dim3(256), 0, stream,
                     C, norms, rowsel, colsel, r_cnt, c_cnt, r_pk, c_pk);

  void* args[] = { (void*)&mu, (void*)&nu, (void*)&r_pk, (void*)&c_pk,
                   (void*)&Upub, (void*)&Vpub, (void*)&stU, (void*)&stV,
                   (void*)&errW, (void*)&costpart };
  hipLaunchCooperativeKernel((const void*)k_sink_coop, dim3(NBLK), dim3(TPB),
                             args, 0, stream);

  hipLaunchKernelGGL(k_final2, dim3(1), dim3(64), 0, stream, costpart, out);
}